// Round 4
// baseline (190.120 us; speedup 1.0000x reference)
//
#include <hip/hip_runtime.h>
#include <math.h>

// VMD: T = 2^20, K = 3, 50 iterations.
// Round-16: FFT chain (127us of 184) is VALU/trans-issue bound (~9x off HBM
// roofline). Changes (k_solve untouched from R15):
//  (1) k_twid: global twiddle table (340 x {w1,w2,w3} x {fwd,inv}), computed
//      once with the SAME sincospif + squaring formulas -> bit-identical stage
//      twiddles; staged to LDS per block (merged into existing barrier).
//  (2) Packed VOP3P butterflies: complex as <2 x float>; cadd/csub 1 pk op,
//      cmul = swap + pk_mul + pk_fma; stage-0 twiddle-free.
//  (3) Output-twiddle recurrence: passA 8 sincospif/thread -> 4 + cmuls;
//      inv_A2 4 -> 2 + cmuls; inv_A2 filter math packed over (freq,-freq).
// Workspace (~40 MB of ~256 MB):
//   [0,8MB)   f_hat (float2, s-layout: s = k1*1024+k2, t(s) = ((k2^512)<<10)|k1)
//   [8,12MB)  ET = |f_hat|^2 transposed: ET[k2*1024 + k1] (float)
//   [12MB..)  W f64[1024*4]; ckeepN float[4096]; omegaF float[4];
//             +64KB: twiddle table float2[2][3][340]
//   [16,32MB) scratch (2 x 8MB float2) -- FFT intermediates

#define ALPHA_F 2000.0f
#define TAU_F   1e-7f

static __device__ __forceinline__ int lpad2(int i) { return i + (i >> 4); }
static __device__ __forceinline__ int swz(int i)  { return ((i & 7) << 7) | (i >> 3); }
static __device__ __forceinline__ int swzA(int i) { return ((i & 7) << 6) | (i >> 3); }
static __device__ __forceinline__ float frcp(float x) { return __builtin_amdgcn_rcpf(x); }

typedef float v2f __attribute__((ext_vector_type(2)));
static __device__ __forceinline__ v2f sp(float s) { v2f r; r.x = s; r.y = s; return r; }
static __device__ __forceinline__ v2f v2(float a, float b) { v2f r; r.x = a; r.y = b; return r; }
static __device__ __forceinline__ v2f pkfma(v2f a, v2f b, v2f c)
{ return __builtin_elementwise_fma(a, b, c); }
// complex mul: (a.x w.x - a.y w.y, a.x w.y + a.y w.x)
static __device__ __forceinline__ v2f cmul(v2f a, v2f w)
{
  v2f t = a * sp(w.x);
  v2f s = v2(-a.y, a.x);
  return pkfma(s, sp(w.y), t);
}

#define PADN2 1088

// ---------------- DPP reductions (VALU pipe only) ----------------
template<int CTRL>
static __device__ __forceinline__ float dpp_addf(float v)
{
  int r = __builtin_amdgcn_update_dpp(0, __float_as_int(v), CTRL, 0xf, 0xf, true);
  return v + __int_as_float(r);
}
static __device__ __forceinline__ float wave64_sum(float v)
{
  v = dpp_addf<0x111>(v);   // row_shr:1
  v = dpp_addf<0x112>(v);   // row_shr:2
  v = dpp_addf<0x114>(v);   // row_shr:4
  v = dpp_addf<0x118>(v);   // row_shr:8
  v = dpp_addf<0x142>(v);   // row_bcast:15
  v = dpp_addf<0x143>(v);   // row_bcast:31 -> lane 63 = full sum
  return v;
}
static __device__ __forceinline__ float row16_sum(float v)
{
  v = dpp_addf<0x111>(v);
  v = dpp_addf<0x112>(v);
  v = dpp_addf<0x114>(v);
  v = dpp_addf<0x118>(v);   // lane 15 of each 16-lane row = row sum
  return v;
}
static __device__ __forceinline__ float rdlane(float v, int l)
{
  return __int_as_float(__builtin_amdgcn_readlane(__float_as_int(v), l));
}

// ---------------- twiddle table: 340 entries per stage-set ------------------
// stage st in {1..4}: base = (4^st - 4)/3 in {0,4,20,84}, size 4^st.
// layout: tw[dir*1020 + {0,340,680} + idx], dir 0 = fwd (w1i=-s), 1 = inv.
__global__ __launch_bounds__(256) void k_twid(float2* __restrict__ tw)
{
  int i = threadIdx.x + blockIdx.x * 256;
  if (i >= 340) return;
  int st, p;
  if (i < 4)       { st = 1; p = i; }
  else if (i < 20) { st = 2; p = i - 4; }
  else if (i < 84) { st = 3; p = i - 20; }
  else             { st = 4; p = i - 84; }
  float sw, cw;
  sincospif((float)(2 * p) * (1.0f / (float)(4 << (2 * st))), &sw, &cw);
#pragma unroll
  for (int dir = 0; dir < 2; ++dir) {
    float w1r = cw, w1i = dir ? sw : -sw;
    float w2r = w1r * w1r - w1i * w1i, w2i = 2.0f * w1r * w1i;
    float w3r = w2r * w1r - w2i * w1i, w3i = w2r * w1i + w2i * w1r;
    float2* b = tw + dir * 1020;
    b[i]       = make_float2(w1r, w1i);
    b[340 + i] = make_float2(w2r, w2i);
    b[680 + i] = make_float2(w3r, w3i);
  }
}

// ---------------- 1024-point radix-4 Stockham FFT, packed math --------------
// twl: LDS copy of the direction's table (w1[340], w2[340], w3[340]).
template<int SIGN>   // -1 = forward, +1 = inverse (unscaled)
static __device__ void fft1024p(v2f* A, v2f* B, const v2f* __restrict__ twl)
{
  const int u = threadIdx.x;
  // ---- stage 0: all twiddles are 1 ----
  {
    v2f X0 = A[lpad2(u)], X1 = A[lpad2(u + 256)];
    v2f X2 = A[lpad2(u + 512)], X3 = A[lpad2(u + 768)];
    v2f t0 = X0 + X2, t1 = X0 - X2, t2 = X1 + X3, t3 = X1 - X3;
    v2f o0 = t0 + t2, o2 = t0 - t2;
    v2f s3 = t3.yx;
    v2f ns3 = v2(s3.x, -s3.y);
    v2f o1, o3;
    if (SIGN < 0) { o1 = t1 + ns3; o3 = t1 - ns3; }
    else          { o1 = t1 - ns3; o3 = t1 + ns3; }
    const int base = u << 2;
    B[lpad2(base    )] = o0; B[lpad2(base + 1)] = o1;
    B[lpad2(base + 2)] = o2; B[lpad2(base + 3)] = o3;
    __syncthreads();
  }
  // ---- stages 1..4: table twiddles ----
#pragma unroll
  for (int st = 1; st < 5; ++st) {
    v2f *in  = (st & 1) ? B : A;
    v2f *out = (st & 1) ? A : B;
    const int quarter = 1 << (2 * st);
    const int p = u & (quarter - 1);
    const int g = u >> (2 * st);
    const int ti = (quarter - 4) / 3 + p;   // {0,4,20,84} + p

    v2f w1 = twl[ti], w2 = twl[340 + ti], w3 = twl[680 + ti];

    v2f X0 = in[lpad2(u)], X1 = in[lpad2(u + 256)];
    v2f X2 = in[lpad2(u + 512)], X3 = in[lpad2(u + 768)];

    v2f y1 = cmul(X1, w1), y2 = cmul(X2, w2), y3 = cmul(X3, w3);

    v2f t0 = X0 + y2, t1 = X0 - y2, t2 = y1 + y3, t3 = y1 - y3;
    v2f o0 = t0 + t2, o2 = t0 - t2;
    v2f s3 = t3.yx;
    v2f ns3 = v2(s3.x, -s3.y);
    v2f o1, o3;
    if (SIGN < 0) { o1 = t1 + ns3; o3 = t1 - ns3; }
    else          { o1 = t1 - ns3; o3 = t1 + ns3; }

    const int base = (g << (2 * st + 2)) + p;
    out[lpad2(base              )] = o0;
    out[lpad2(base +     quarter)] = o1;
    out[lpad2(base + 2 * quarter)] = o2;
    out[lpad2(base + 3 * quarter)] = o3;
    __syncthreads();
  }
}

#define STAGE_TW(dst, src) \
  for (int i_ = threadIdx.x; i_ < 510; i_ += 256) \
    ((float4*)(dst))[i_] = ((const float4*)(src))[i_];

// ---------------- forward passA: packed-real, 2 columns per block ----------
__global__ __launch_bounds__(256) void k_fwd_passA(const float* __restrict__ x,
                                                   const float2* __restrict__ twg,
                                                   float2* __restrict__ ws0)
{
  __shared__ __align__(16) v2f A[PADN2], B[PADN2];
  __shared__ __align__(16) v2f twl[1020];
  const int p = swzA(blockIdx.x);     // 512 blocks; column pair (2p, 2p+1)
  const int tid = threadIdx.x;
  const int c0 = 2 * p;
  STAGE_TW(twl, twg);                 // forward table
#pragma unroll
  for (int q = 0; q < 4; ++q) {
    int j = tid + 256 * q;            // n1
    A[lpad2(j)] = ((const v2f*)x)[(size_t)j * 512 + p];
  }
  __syncthreads();
  fft1024p<-1>(A, B, twl);

  // output twiddles by recurrence: z0(q) = c0*(tid+256q)*2^-19 steps c0/2048
  float sa, ca, sb, cb, ssa, cca, ssb, ccb;
  sincospif((float)(c0 * tid) * (2.0f / 1048576.0f), &sa, &ca);
  sincospif((float)((c0 + 1) * tid) * (2.0f / 1048576.0f), &sb, &cb);
  sincospif((float)c0 * (1.0f / 2048.0f), &ssa, &cca);
  sincospif((float)(c0 + 1) * (1.0f / 2048.0f), &ssb, &ccb);
  v2f E0 = v2(ca, -sa), E1 = v2(cb, -sb);
  const v2f S0 = v2(cca, -ssa), S1 = v2(ccb, -ssb);
#pragma unroll
  for (int q = 0; q < 4; ++q) {
    int k = tid + 256 * q;
    int kk = (1024 - k) & 1023;
    v2f Z = B[lpad2(k)];
    v2f Wv = B[lpad2(kk)];
    // X0 = (Z + conj(W))/2 ; X1 = (Z - conj(W))/(2i)
    float X0r = 0.5f * (Z.x + Wv.x), X0i = 0.5f * (Z.y - Wv.y);
    float X1r = 0.5f * (Z.y + Wv.y), X1i = 0.5f * (Wv.x - Z.x);
    v2f o01 = cmul(v2(X0r, X0i), E0);   // E = (c,-s): (Xr c + Xi s, Xi c - Xr s)
    v2f o23 = cmul(v2(X1r, X1i), E1);
    float4 o = make_float4(o01.x, o01.y, o23.x, o23.y);
    ((float4*)ws0)[(size_t)k * 512 + p] = o;   // ws0[k*1024 + c0 .. c0+1]
    E0 = cmul(E0, S0); E1 = cmul(E1, S1);
  }
}

// ---------------- forward passB: contiguous reads; stores fhat + E^T --------
__global__ __launch_bounds__(256) void k_fwd_passB(const float2* __restrict__ ws0,
                                                   const float2* __restrict__ twg,
                                                   float2* __restrict__ fhat,
                                                   float* __restrict__ ET)
{
  __shared__ __align__(16) v2f A[PADN2], B[PADN2];
  __shared__ __align__(16) v2f twl[1020];
  const int b = swz(blockIdx.x);   // k1
  const int tid = threadIdx.x;
  STAGE_TW(twl, twg);
#pragma unroll
  for (int q = 0; q < 4; ++q) {
    int j = tid + 256 * q;         // n2 ; contiguous read
    A[lpad2(j)] = ((const v2f*)ws0)[(size_t)b * 1024 + j];
  }
  __syncthreads();
  fft1024p<-1>(A, B, twl);
#pragma unroll
  for (int q = 0; q < 4; ++q) {
    int k2 = tid + 256 * q;
    v2f v = B[lpad2(k2)];
    fhat[(size_t)b * 1024 + k2] = make_float2(v.x, v.y);
    ET[(size_t)k2 * 1024 + b] = v.x * v.x + v.y * v.y;  // strided store (cheap)
  }
}

// ---------------- Lagrange basis on nodes x = {0, 1/3, 2/3, 1} --------------
static __device__ __forceinline__ void lag4(float x, float& l0, float& l1,
                                            float& l2, float& l3)
{
  float m0 = x, m1 = x - (1.0f / 3.0f), m2 = x - (2.0f / 3.0f), m3 = x - 1.0f;
  l0 = -4.5f * m1 * m2 * m3;
  l1 = 13.5f * m0 * m2 * m3;
  l2 = -13.5f * m0 * m1 * m3;
  l3 =  4.5f * m0 * m1 * m2;
}

// ---------------- bin weights from E^T (fully contiguous reads) -------------
__global__ __launch_bounds__(256) void k_moments(const float* __restrict__ ET,
                                                 double* __restrict__ W)
{
  __shared__ double red[4 * 4];
  const int B = blockIdx.x;        // bin
  const int k2 = B ^ 512;
  const int tid = threadIdx.x;
  double a0 = 0, a1 = 0, a2 = 0, a3 = 0;
#pragma unroll
  for (int q = 0; q < 4; ++q) {
    int k1 = tid + 256 * q;
    float e = ET[(size_t)k2 * 1024 + k1];   // contiguous
    float l0, l1, l2, l3;
    lag4((float)k1 * (1.0f / 1024.0f), l0, l1, l2, l3);
    a0 += (double)(e * l0); a1 += (double)(e * l1);
    a2 += (double)(e * l2); a3 += (double)(e * l3);
  }
  const int lane = tid & 63, wv = tid >> 6;       // 4 waves
  double pv[4] = { a0, a1, a2, a3 };
#pragma unroll
  for (int j = 0; j < 4; ++j) {
    double v = pv[j];
    for (int off = 32; off; off >>= 1) v += __shfl_down(v, off, 64);
    if (lane == 0) red[wv * 4 + j] = v;
  }
  __syncthreads();
  if (tid < 4)
    W[B * 4 + tid] = red[tid] + red[4 + tid] + red[8 + tid] + red[12 + tid];
}

// ---------------- the whole solve loop in ONE workgroup ---------------------
// 1024 threads (16 waves); thread t owns bin t (4 cubic nodes, as 2 packed
// pairs). ONE barrier per iteration (red[] double-buffered). Packed fp32 math.
__global__ __launch_bounds__(1024) void k_solve(
    const double* __restrict__ W4, const float* __restrict__ omega_init,
    float* __restrict__ ckeepN, float* __restrict__ omegaF)
{
  __shared__ float red[2][6 * 16];   // [buf][slot*16 + wave]
  const int t = threadIdx.x;
  const int lane = t & 63, wv = t >> 6;    // 16 waves

  float Wsc[4], fsc[4];
#pragma unroll
  for (int e = 0; e < 4; ++e) {
    Wsc[e] = (float)W4[t * 4 + e];
    fsc[e] = (float)((double)t / 1024.0 + (double)e / 3072.0 - 0.5);
  }
  const v2f frP = v2(fsc[0], fsc[1]), frQ = v2(fsc[2], fsc[3]);
  const v2f WrP = v2(Wsc[0], Wsc[1]), WrQ = v2(Wsc[2], Wsc[3]);
  const v2f WfP = WrP * frP,          WfQ = WrQ * frQ;
  v2f cnrP = sp(0.0f), cnrQ = sp(0.0f);

  float om0 = omega_init[0], om1 = omega_init[1], om2 = omega_init[2];

#pragma unroll 1
  for (int it = 0; it < 49; ++it) {        // n = 0 .. 48
    float* rb = red[it & 1];
    v2f p0 = sp(0.f), p1 = sp(0.f), p2 = sp(0.f),
        p3 = sp(0.f), p4 = sp(0.f), p5 = sp(0.f);

    auto node_pair = [&](const v2f fv, const v2f Wrv, const v2f Wfv, v2f& cnv) {
      v2f a0 = fv - sp(om0), a1 = fv - sp(om1), a2 = fv - sp(om2);
      v2f d0 = a0 * a0, d1 = a1 * a1, d2 = a2 * a2;
      v2f s01 = d0 + d1, s12 = d1 + d2;
      v2f dA = pkfma(sp(ALPHA_F), s01, sp(1.0f));   // 1 + a(d0+d1)
      v2f dC = pkfma(sp(ALPHA_F), s12, sp(1.0f));   // 1 + a(d1+d2)
      v2f dB = pkfma(sp(ALPHA_F), d2, dA);          // 1 + a(d0+d1+d2)
      v2f AB = dA * dB, BC = dB * dC, AC = dA * dC;
      v2f ABC = AB * dC;
      v2f r = v2(frcp(ABC.x), frcp(ABC.y));         // scalar rcps
      v2f w0 = BC * r, w1 = AC * r, w2 = AB * r;
      v2f hf = pkfma(sp(-0.5f), cnv, sp(1.0f));
      v2f g = hf * hf;
      v2f gw0 = g * (w0 * w0), gw1 = g * (w1 * w1), gw2 = g * (w2 * w2);
      p0 = pkfma(Wfv, gw0, p0); p1 = pkfma(Wfv, gw1, p1); p2 = pkfma(Wfv, gw2, p2);
      p3 = pkfma(Wrv, gw0, p3); p4 = pkfma(Wrv, gw1, p4); p5 = pkfma(Wrv, gw2, p5);
      v2f S = (w0 + w1) + w2;
      cnv = pkfma(sp(TAU_F), pkfma(S, hf, sp(-1.0f)), cnv);
    };
    node_pair(frP, WrP, WfP, cnrP);
    node_pair(frQ, WrQ, WfQ, cnrQ);

    float q0 = p0.x + p0.y, q1 = p1.x + p1.y, q2 = p2.x + p2.y;
    float q3 = p3.x + p3.y, q4 = p4.x + p4.y, q5 = p5.x + p5.y;

    q0 = wave64_sum(q0); q1 = wave64_sum(q1); q2 = wave64_sum(q2);
    q3 = wave64_sum(q3); q4 = wave64_sum(q4); q5 = wave64_sum(q5);
    if (lane == 63) {
      rb[0 * 16 + wv] = q0; rb[1 * 16 + wv] = q1; rb[2 * 16 + wv] = q2;
      rb[3 * 16 + wv] = q3; rb[4 * 16 + wv] = q4; rb[5 * 16 + wv] = q5;
    }
    __syncthreads();                 // the ONLY barrier in the iteration
    // stage 2, redundantly per wave: slots 0..3 from v1, slots 4..5 from v2
    float v1 = rb[lane];                     // red[slot(lane>>4)*16 + (lane&15)]
    float v2_ = rb[64 + (lane & 31)];        // slots 4,5 (lanes 32..63 dup)
    v1 = row16_sum(v1);
    v2_ = row16_sum(v2_);
    float n0 = rdlane(v1, 15), n1 = rdlane(v1, 31), n2 = rdlane(v1, 47);
    float e0 = rdlane(v1, 63), e1 = rdlane(v2_, 15), e2 = rdlane(v2_, 31);
    om0 = n0 * frcp(e0);
    om1 = n1 * frcp(e1);
    om2 = n2 * frcp(e2);
  }

  // entry state of n = 49 (same layout as before: node id = bin*4 + j)
  ((float4*)ckeepN)[t] = make_float4(cnrP.x, cnrP.y, cnrQ.x, cnrQ.y);
  if (t == 0) { omegaF[0] = om0; omegaF[1] = om1; omegaF[2] = om2; }
}

// ---------------- inverse passA: pk=0 -> V0 + i*V1 packed ; pk=1 -> V2 ------
__global__ __launch_bounds__(256) void k_inv_A2(
    const float2* __restrict__ fhat, const float* __restrict__ ckeepN,
    const float* __restrict__ omegaF, const float2* __restrict__ twg,
    float2* __restrict__ ws0)
{
  __shared__ __align__(16) v2f A[PADN2], B[PADN2];
  __shared__ __align__(16) v2f twl[1020];
  __shared__ float cn4[4096];
  __shared__ float som[3];
  const int tid = threadIdx.x;
  const int pk = blockIdx.x >> 10;
  const int b = swz(blockIdx.x & 1023);   // k1 of s-layout
  STAGE_TW(twl, twg);                     // inverse table
  for (int i = tid; i < 4096; i += 256) cn4[i] = ckeepN[i];
  if (tid == 0) { som[0] = omegaF[0]; som[1] = omegaF[1]; som[2] = omegaF[2]; }
  __syncthreads();
  const float om0 = som[0], om1 = som[1], om2 = som[2];
  const float xb = (float)b * (1.0f / 1024.0f);
  float l0, l1, l2, l3, m0, m1, m2, m3;
  lag4(xb, l0, l1, l2, l3);
  lag4(1.0f - xb, m0, m1, m2, m3);

#pragma unroll
  for (int q = 0; q < 4; ++q) {
    int j = tid + 256 * q;       // k2
    float2 f = fhat[(size_t)b * 1024 + j];
    int bin = j ^ 512;
    int binp = 1023 - bin;
    float4 cv = ((const float4*)cn4)[bin];
    float4 cw = ((const float4*)cn4)[binp];
    float c  = l0 * cv.x + l1 * cv.y + l2 * cv.z + l3 * cv.w;
    float cp = m0 * cw.x + m1 * cw.y + m2 * cw.z + m3 * cw.w;
    float hf = 1.0f - 0.5f * c;
    float hp = 1.0f - 0.5f * cp;
    int tt = (bin << 10) | b;
    float freq = (float)tt * (1.0f / 1048576.0f) - 0.5f;
    v2f fpm = v2(freq, -freq);           // .x: +freq terms (d), .y: -freq (e)
    v2f A0 = fpm - sp(om0), A1 = fpm - sp(om1), A2v = fpm - sp(om2);
    v2f D0 = A0 * A0, D1 = A1 * A1, D2 = A2v * A2v;
    v2f V;
    if (pk == 0) {
      v2f DA = pkfma(sp(ALPHA_F), D0 + D1, sp(1.0f));
      v2f DB = pkfma(sp(ALPHA_F), D2, DA);
      float r0 = hf * frcp(DA.x), r0n = hp * frcp(DA.y);
      float r1 = hf * frcp(DB.x), r1n = hp * frcp(DB.y);
      float Rr = 0.5f * (r0 + r0n), Ri = 0.5f * (r1 + r1n);
      V = cmul(v2(f.x, f.y), v2(Rr, Ri));
    } else {
      v2f DC = pkfma(sp(ALPHA_F), D1 + D2, sp(1.0f));
      float r2 = hf * frcp(DC.x), r2n = hp * frcp(DC.y);
      float Rr = 0.5f * (r2 + r2n);
      V = v2(f.x, f.y) * sp(Rr);
    }
    A[lpad2(j)] = V;
  }
  __syncthreads();
  fft1024p<1>(A, B, twl);

  // output twiddle by recurrence: z(q) = b*(tid+256q)*2^-19, step b/2048
  float sa, ca, ss, cs;
  sincospif((float)(b * tid) * (2.0f / 1048576.0f), &sa, &ca);
  sincospif((float)b * (1.0f / 2048.0f), &ss, &cs);
  v2f E = v2(ca, sa);
  const v2f S = v2(cs, ss);
#pragma unroll
  for (int q = 0; q < 4; ++q) {
    int m1i = tid + 256 * q;
    v2f v = B[lpad2(m1i)];
    v2f o = cmul(v, E);                  // (vx c - vy s, vy c + vx s)
    ws0[(size_t)pk * 1048576 + (size_t)m1i * 1024 + b] = make_float2(o.x, o.y);
    E = cmul(E, S);
  }
}

// ---------------- inverse passB: pk=0 -> out0=Re,out1=Im ; pk=1 -> out2=Re --
__global__ __launch_bounds__(256) void k_inv_B2(const float2* __restrict__ ws0,
                                                const float2* __restrict__ twg,
                                                float* __restrict__ out)
{
  __shared__ __align__(16) v2f A[PADN2], B[PADN2];
  __shared__ __align__(16) v2f twl[1020];
  const int pk = blockIdx.x >> 10;
  const int b = swz(blockIdx.x & 1023);   // m1
  const int tid = threadIdx.x;
  STAGE_TW(twl, twg);
#pragma unroll
  for (int q = 0; q < 4; ++q) {
    int j = tid + 256 * q;       // contiguous read of row m1=b
    A[lpad2(j)] = ((const v2f*)ws0)[(size_t)pk * 1048576 + (size_t)b * 1024 + j];
  }
  __syncthreads();
  fft1024p<1>(A, B, twl);
  const float sc = 1.0f / 1048576.0f;
#pragma unroll
  for (int q = 0; q < 4; ++q) {
    int m2 = tid + 256 * q;
    v2f v = B[lpad2(m2)];
    if (pk == 0) {
      out[(size_t)m2 * 1024 + b]           = v.x * sc;   // imf0
      out[1048576 + (size_t)m2 * 1024 + b] = v.y * sc;   // imf1
    } else {
      out[2097152 + (size_t)m2 * 1024 + b] = v.x * sc;   // imf2
    }
  }
}

// ---------------- host launch ----------------
extern "C" void kernel_launch(void* const* d_in, const int* in_sizes, int n_in,
                              void* d_out, int out_size, void* d_ws, size_t ws_size,
                              hipStream_t stream)
{
  (void)in_sizes; (void)n_in; (void)out_size; (void)ws_size;
  const float* x       = (const float*)d_in[0];
  const float* om_init = (const float*)d_in[1];
  float* out = (float*)d_out;

  char* w = (char*)d_ws;
  const size_t MB = 1024ull * 1024ull;
  float2* fhat     = (float2*)(w);
  float*  ET       = (float*)(w + 8 * MB);
  double* W4       = (double*)(w + 12 * MB);            // 4096 doubles (32 KB)
  float*  ckeepN   = (float*)(w + 12 * MB + 32 * 1024); // 4096 floats (16 KB)
  float*  omegaF   = (float*)(w + 12 * MB + 48 * 1024);
  float2* tw       = (float2*)(w + 12 * MB + 64 * 1024); // 2040 float2 (16 KB)
  float2* scratch  = (float2*)(w + 16 * MB);            // 2 x 8 MB

  k_twid<<<2, 256, 0, stream>>>(tw);
  k_fwd_passA<<<512, 256, 0, stream>>>(x, tw, scratch);
  k_fwd_passB<<<1024, 256, 0, stream>>>(scratch, tw, fhat, ET);
  k_moments<<<1024, 256, 0, stream>>>(ET, W4);
  k_solve<<<1, 1024, 0, stream>>>(W4, om_init, ckeepN, omegaF);
  k_inv_A2<<<2048, 256, 0, stream>>>(fhat, ckeepN, omegaF, tw + 1020, scratch);
  k_inv_B2<<<2048, 256, 0, stream>>>(scratch, tw + 1020, out);
}

// Round 5
// 183.155 us; speedup vs baseline: 1.0380x; 1.0380x over previous
//
#include <hip/hip_runtime.h>
#include <math.h>

// VMD: T = 2^20, K = 3, 50 iterations.
// Round-17: R16 post-mortem -- twiddle TABLE regressed the FFT chain (-6.4us):
// FFT kernels are LATENCY-bound at 2-8 blocks/CU; inline sincospif twiddles
// depend only on tid and hide under the butterfly ds_read latency, while table
// reads ADD 3 dependent LDS reads per stage + 8KB LDS occupancy loss + one
// extra launch. Changes:
//  (1) revert to inline-sincospif twiddles (R15 formulas) inside the packed
//      VOP3P butterflies; k_twid/table deleted.
//  (2) fuse inv_A2 pk=0/pk=1 into ONE 1024-block kernel doing 2 sequential
//      FFTs with the fhat row held in registers: halves fhat reads, cn4
//      staging, interp/denominator math, and block count. Formula-identical.
// Workspace (~40 MB of ~256 MB):
//   [0,8MB)   f_hat (float2, s-layout: s = k1*1024+k2, t(s) = ((k2^512)<<10)|k1)
//   [8,12MB)  ET = |f_hat|^2 transposed: ET[k2*1024 + k1] (float)
//   [12MB..)  W f64[1024*4]; ckeepN float[4096]; omegaF float[4]
//   [16,32MB) scratch (2 x 8MB float2) -- FFT intermediates

#define ALPHA_F 2000.0f
#define TAU_F   1e-7f

static __device__ __forceinline__ int lpad2(int i) { return i + (i >> 4); }
static __device__ __forceinline__ int swz(int i)  { return ((i & 7) << 7) | (i >> 3); }
static __device__ __forceinline__ int swzA(int i) { return ((i & 7) << 6) | (i >> 3); }
static __device__ __forceinline__ float frcp(float x) { return __builtin_amdgcn_rcpf(x); }

typedef float v2f __attribute__((ext_vector_type(2)));
static __device__ __forceinline__ v2f sp(float s) { v2f r; r.x = s; r.y = s; return r; }
static __device__ __forceinline__ v2f v2(float a, float b) { v2f r; r.x = a; r.y = b; return r; }
static __device__ __forceinline__ v2f pkfma(v2f a, v2f b, v2f c)
{ return __builtin_elementwise_fma(a, b, c); }
// complex mul: (a.x w.x - a.y w.y, a.x w.y + a.y w.x)
static __device__ __forceinline__ v2f cmul(v2f a, v2f w)
{
  v2f t = a * sp(w.x);
  v2f s = v2(-a.y, a.x);
  return pkfma(s, sp(w.y), t);
}
static __device__ __forceinline__ v2f cmulrr(v2f a, float wr, float wi)
{
  v2f t = a * sp(wr);
  v2f s = v2(-a.y, a.x);
  return pkfma(s, sp(wi), t);
}

#define PADN2 1088

// ---------------- DPP reductions (VALU pipe only) ----------------
template<int CTRL>
static __device__ __forceinline__ float dpp_addf(float v)
{
  int r = __builtin_amdgcn_update_dpp(0, __float_as_int(v), CTRL, 0xf, 0xf, true);
  return v + __int_as_float(r);
}
static __device__ __forceinline__ float wave64_sum(float v)
{
  v = dpp_addf<0x111>(v);   // row_shr:1
  v = dpp_addf<0x112>(v);   // row_shr:2
  v = dpp_addf<0x114>(v);   // row_shr:4
  v = dpp_addf<0x118>(v);   // row_shr:8
  v = dpp_addf<0x142>(v);   // row_bcast:15
  v = dpp_addf<0x143>(v);   // row_bcast:31 -> lane 63 = full sum
  return v;
}
static __device__ __forceinline__ float row16_sum(float v)
{
  v = dpp_addf<0x111>(v);
  v = dpp_addf<0x112>(v);
  v = dpp_addf<0x114>(v);
  v = dpp_addf<0x118>(v);   // lane 15 of each 16-lane row = row sum
  return v;
}
static __device__ __forceinline__ float rdlane(float v, int l)
{
  return __int_as_float(__builtin_amdgcn_readlane(__float_as_int(v), l));
}

// ---------------- 1024-point radix-4 Stockham FFT, packed math --------------
// Inline sincospif twiddles (tid-only -> issue in parallel with ds_reads).
template<int SIGN>   // -1 = forward, +1 = inverse (unscaled)
static __device__ void fft1024p(v2f* A, v2f* B)   // in A, out B
{
  const int u = threadIdx.x;
  // ---- stage 0: all twiddles are 1 ----
  {
    v2f X0 = A[lpad2(u)], X1 = A[lpad2(u + 256)];
    v2f X2 = A[lpad2(u + 512)], X3 = A[lpad2(u + 768)];
    v2f t0 = X0 + X2, t1 = X0 - X2, t2 = X1 + X3, t3 = X1 - X3;
    v2f o0 = t0 + t2, o2 = t0 - t2;
    v2f ns3 = v2(t3.y, -t3.x);
    v2f o1, o3;
    if (SIGN < 0) { o1 = t1 + ns3; o3 = t1 - ns3; }
    else          { o1 = t1 - ns3; o3 = t1 + ns3; }
    const int base = u << 2;
    B[lpad2(base    )] = o0; B[lpad2(base + 1)] = o1;
    B[lpad2(base + 2)] = o2; B[lpad2(base + 3)] = o3;
    __syncthreads();
  }
  // ---- stages 1..4: inline twiddles ----
#pragma unroll
  for (int st = 1; st < 5; ++st) {
    v2f *in  = (st & 1) ? B : A;
    v2f *out = (st & 1) ? A : B;
    const int quarter = 1 << (2 * st);
    const int p = u & (quarter - 1);
    const int g = u >> (2 * st);

    float sw, cw;
    sincospif((float)(2 * p) * (1.0f / (float)(4 << (2 * st))), &sw, &cw);
    const float w1r = cw, w1i = (SIGN < 0) ? -sw : sw;
    const float w2r = w1r * w1r - w1i * w1i, w2i = 2.0f * w1r * w1i;
    const float w3r = w2r * w1r - w2i * w1i, w3i = w2r * w1i + w2i * w1r;

    v2f X0 = in[lpad2(u)], X1 = in[lpad2(u + 256)];
    v2f X2 = in[lpad2(u + 512)], X3 = in[lpad2(u + 768)];

    v2f y1 = cmulrr(X1, w1r, w1i), y2 = cmulrr(X2, w2r, w2i),
        y3 = cmulrr(X3, w3r, w3i);

    v2f t0 = X0 + y2, t1 = X0 - y2, t2 = y1 + y3, t3 = y1 - y3;
    v2f o0 = t0 + t2, o2 = t0 - t2;
    v2f ns3 = v2(t3.y, -t3.x);
    v2f o1, o3;
    if (SIGN < 0) { o1 = t1 + ns3; o3 = t1 - ns3; }
    else          { o1 = t1 - ns3; o3 = t1 + ns3; }

    const int base = (g << (2 * st + 2)) + p;
    out[lpad2(base              )] = o0;
    out[lpad2(base +     quarter)] = o1;
    out[lpad2(base + 2 * quarter)] = o2;
    out[lpad2(base + 3 * quarter)] = o3;
    __syncthreads();
  }
}

// ---------------- forward passA: packed-real, 2 columns per block ----------
// z_j = x[j][2p] + i*x[j][2p+1]; after FFT, Hermitian split recovers both
// column spectra; twiddle each (recurrence); one float4 store writes both.
__global__ __launch_bounds__(256) void k_fwd_passA(const float* __restrict__ x,
                                                   float2* __restrict__ ws0)
{
  __shared__ __align__(16) v2f A[PADN2], B[PADN2];
  const int p = swzA(blockIdx.x);     // 512 blocks; column pair (2p, 2p+1)
  const int tid = threadIdx.x;
  const int c0 = 2 * p;
#pragma unroll
  for (int q = 0; q < 4; ++q) {
    int j = tid + 256 * q;            // n1
    A[lpad2(j)] = ((const v2f*)x)[(size_t)j * 512 + p];
  }
  __syncthreads();
  fft1024p<-1>(A, B);

  // output twiddles by recurrence: step c0/2048 (and (c0+1)/2048)
  float sa, ca, sb, cb, ssa, cca, ssb, ccb;
  sincospif((float)(c0 * tid) * (2.0f / 1048576.0f), &sa, &ca);
  sincospif((float)((c0 + 1) * tid) * (2.0f / 1048576.0f), &sb, &cb);
  sincospif((float)c0 * (1.0f / 2048.0f), &ssa, &cca);
  sincospif((float)(c0 + 1) * (1.0f / 2048.0f), &ssb, &ccb);
  v2f E0 = v2(ca, -sa), E1 = v2(cb, -sb);
  const v2f S0 = v2(cca, -ssa), S1 = v2(ccb, -ssb);
#pragma unroll
  for (int q = 0; q < 4; ++q) {
    int k = tid + 256 * q;
    int kk = (1024 - k) & 1023;
    v2f Z = B[lpad2(k)];
    v2f Wv = B[lpad2(kk)];
    // X0 = (Z + conj(W))/2 ; X1 = (Z - conj(W))/(2i)
    float X0r = 0.5f * (Z.x + Wv.x), X0i = 0.5f * (Z.y - Wv.y);
    float X1r = 0.5f * (Z.y + Wv.y), X1i = 0.5f * (Wv.x - Z.x);
    v2f o01 = cmul(v2(X0r, X0i), E0);
    v2f o23 = cmul(v2(X1r, X1i), E1);
    float4 o = make_float4(o01.x, o01.y, o23.x, o23.y);
    ((float4*)ws0)[(size_t)k * 512 + p] = o;   // ws0[k*1024 + c0 .. c0+1]
    E0 = cmul(E0, S0); E1 = cmul(E1, S1);
  }
}

// ---------------- forward passB: contiguous reads; stores fhat + E^T --------
__global__ __launch_bounds__(256) void k_fwd_passB(const float2* __restrict__ ws0,
                                                   float2* __restrict__ fhat,
                                                   float* __restrict__ ET)
{
  __shared__ __align__(16) v2f A[PADN2], B[PADN2];
  const int b = swz(blockIdx.x);   // k1
  const int tid = threadIdx.x;
#pragma unroll
  for (int q = 0; q < 4; ++q) {
    int j = tid + 256 * q;         // n2 ; contiguous read
    A[lpad2(j)] = ((const v2f*)ws0)[(size_t)b * 1024 + j];
  }
  __syncthreads();
  fft1024p<-1>(A, B);
#pragma unroll
  for (int q = 0; q < 4; ++q) {
    int k2 = tid + 256 * q;
    v2f v = B[lpad2(k2)];
    fhat[(size_t)b * 1024 + k2] = make_float2(v.x, v.y);
    ET[(size_t)k2 * 1024 + b] = v.x * v.x + v.y * v.y;  // strided store (cheap)
  }
}

// ---------------- Lagrange basis on nodes x = {0, 1/3, 2/3, 1} --------------
static __device__ __forceinline__ void lag4(float x, float& l0, float& l1,
                                            float& l2, float& l3)
{
  float m0 = x, m1 = x - (1.0f / 3.0f), m2 = x - (2.0f / 3.0f), m3 = x - 1.0f;
  l0 = -4.5f * m1 * m2 * m3;
  l1 = 13.5f * m0 * m2 * m3;
  l2 = -13.5f * m0 * m1 * m3;
  l3 =  4.5f * m0 * m1 * m2;
}

// ---------------- bin weights from E^T (fully contiguous reads) -------------
__global__ __launch_bounds__(256) void k_moments(const float* __restrict__ ET,
                                                 double* __restrict__ W)
{
  __shared__ double red[4 * 4];
  const int B = blockIdx.x;        // bin
  const int k2 = B ^ 512;
  const int tid = threadIdx.x;
  double a0 = 0, a1 = 0, a2 = 0, a3 = 0;
#pragma unroll
  for (int q = 0; q < 4; ++q) {
    int k1 = tid + 256 * q;
    float e = ET[(size_t)k2 * 1024 + k1];   // contiguous
    float l0, l1, l2, l3;
    lag4((float)k1 * (1.0f / 1024.0f), l0, l1, l2, l3);
    a0 += (double)(e * l0); a1 += (double)(e * l1);
    a2 += (double)(e * l2); a3 += (double)(e * l3);
  }
  const int lane = tid & 63, wv = tid >> 6;       // 4 waves
  double pv[4] = { a0, a1, a2, a3 };
#pragma unroll
  for (int j = 0; j < 4; ++j) {
    double v = pv[j];
    for (int off = 32; off; off >>= 1) v += __shfl_down(v, off, 64);
    if (lane == 0) red[wv * 4 + j] = v;
  }
  __syncthreads();
  if (tid < 4)
    W[B * 4 + tid] = red[tid] + red[4 + tid] + red[8 + tid] + red[12 + tid];
}

// ---------------- the whole solve loop in ONE workgroup ---------------------
// 1024 threads (16 waves); thread t owns bin t (4 cubic nodes, as 2 packed
// pairs). ONE barrier per iteration (red[] double-buffered). Packed fp32 math.
__global__ __launch_bounds__(1024) void k_solve(
    const double* __restrict__ W4, const float* __restrict__ omega_init,
    float* __restrict__ ckeepN, float* __restrict__ omegaF)
{
  __shared__ float red[2][6 * 16];   // [buf][slot*16 + wave]
  const int t = threadIdx.x;
  const int lane = t & 63, wv = t >> 6;    // 16 waves

  float Wsc[4], fsc[4];
#pragma unroll
  for (int e = 0; e < 4; ++e) {
    Wsc[e] = (float)W4[t * 4 + e];
    fsc[e] = (float)((double)t / 1024.0 + (double)e / 3072.0 - 0.5);
  }
  const v2f frP = v2(fsc[0], fsc[1]), frQ = v2(fsc[2], fsc[3]);
  const v2f WrP = v2(Wsc[0], Wsc[1]), WrQ = v2(Wsc[2], Wsc[3]);
  const v2f WfP = WrP * frP,          WfQ = WrQ * frQ;
  v2f cnrP = sp(0.0f), cnrQ = sp(0.0f);

  float om0 = omega_init[0], om1 = omega_init[1], om2 = omega_init[2];

#pragma unroll 1
  for (int it = 0; it < 49; ++it) {        // n = 0 .. 48
    float* rb = red[it & 1];
    v2f p0 = sp(0.f), p1 = sp(0.f), p2 = sp(0.f),
        p3 = sp(0.f), p4 = sp(0.f), p5 = sp(0.f);

    auto node_pair = [&](const v2f fv, const v2f Wrv, const v2f Wfv, v2f& cnv) {
      v2f a0 = fv - sp(om0), a1 = fv - sp(om1), a2 = fv - sp(om2);
      v2f d0 = a0 * a0, d1 = a1 * a1, d2 = a2 * a2;
      v2f s01 = d0 + d1, s12 = d1 + d2;
      v2f dA = pkfma(sp(ALPHA_F), s01, sp(1.0f));   // 1 + a(d0+d1)
      v2f dC = pkfma(sp(ALPHA_F), s12, sp(1.0f));   // 1 + a(d1+d2)
      v2f dB = pkfma(sp(ALPHA_F), d2, dA);          // 1 + a(d0+d1+d2)
      v2f AB = dA * dB, BC = dB * dC, AC = dA * dC;
      v2f ABC = AB * dC;
      v2f r = v2(frcp(ABC.x), frcp(ABC.y));         // scalar rcps
      v2f w0 = BC * r, w1 = AC * r, w2 = AB * r;
      v2f hf = pkfma(sp(-0.5f), cnv, sp(1.0f));
      v2f g = hf * hf;
      v2f gw0 = g * (w0 * w0), gw1 = g * (w1 * w1), gw2 = g * (w2 * w2);
      p0 = pkfma(Wfv, gw0, p0); p1 = pkfma(Wfv, gw1, p1); p2 = pkfma(Wfv, gw2, p2);
      p3 = pkfma(Wrv, gw0, p3); p4 = pkfma(Wrv, gw1, p4); p5 = pkfma(Wrv, gw2, p5);
      v2f S = (w0 + w1) + w2;
      cnv = pkfma(sp(TAU_F), pkfma(S, hf, sp(-1.0f)), cnv);
    };
    node_pair(frP, WrP, WfP, cnrP);
    node_pair(frQ, WrQ, WfQ, cnrQ);

    float q0 = p0.x + p0.y, q1 = p1.x + p1.y, q2 = p2.x + p2.y;
    float q3 = p3.x + p3.y, q4 = p4.x + p4.y, q5 = p5.x + p5.y;

    q0 = wave64_sum(q0); q1 = wave64_sum(q1); q2 = wave64_sum(q2);
    q3 = wave64_sum(q3); q4 = wave64_sum(q4); q5 = wave64_sum(q5);
    if (lane == 63) {
      rb[0 * 16 + wv] = q0; rb[1 * 16 + wv] = q1; rb[2 * 16 + wv] = q2;
      rb[3 * 16 + wv] = q3; rb[4 * 16 + wv] = q4; rb[5 * 16 + wv] = q5;
    }
    __syncthreads();                 // the ONLY barrier in the iteration
    // stage 2, redundantly per wave: slots 0..3 from v1, slots 4..5 from v2
    float v1 = rb[lane];                     // red[slot(lane>>4)*16 + (lane&15)]
    float v2_ = rb[64 + (lane & 31)];        // slots 4,5 (lanes 32..63 dup)
    v1 = row16_sum(v1);
    v2_ = row16_sum(v2_);
    float n0 = rdlane(v1, 15), n1 = rdlane(v1, 31), n2 = rdlane(v1, 47);
    float e0 = rdlane(v1, 63), e1 = rdlane(v2_, 15), e2 = rdlane(v2_, 31);
    om0 = n0 * frcp(e0);
    om1 = n1 * frcp(e1);
    om2 = n2 * frcp(e2);
  }

  // entry state of n = 49 (same layout as before: node id = bin*4 + j)
  ((float4*)ckeepN)[t] = make_float4(cnrP.x, cnrP.y, cnrQ.x, cnrQ.y);
  if (t == 0) { omegaF[0] = om0; omegaF[1] = om1; omegaF[2] = om2; }
}

// ---------------- inverse passA (FUSED): both planes per block --------------
// Block b: loads fhat row once into regs, builds V0+i*V1 (plane 0) -> FFT ->
// store; rebuilds A with V2 (plane 1) from regs -> FFT -> store. Filter math
// formula-identical to the old pk=0/pk=1 split; shared c/cp/D0..D2.
__global__ __launch_bounds__(256) void k_inv_A2(
    const float2* __restrict__ fhat, const float* __restrict__ ckeepN,
    const float* __restrict__ omegaF, float2* __restrict__ ws0)
{
  __shared__ __align__(16) v2f A[PADN2], B[PADN2];
  __shared__ float cn4[4096];
  __shared__ float som[3];
  const int tid = threadIdx.x;
  const int b = swz(blockIdx.x);          // 1024 blocks; k1 of s-layout
  for (int i = tid; i < 4096; i += 256) cn4[i] = ckeepN[i];
  if (tid == 0) { som[0] = omegaF[0]; som[1] = omegaF[1]; som[2] = omegaF[2]; }
  __syncthreads();
  const float om0 = som[0], om1 = som[1], om2 = som[2];
  const float xb = (float)b * (1.0f / 1024.0f);
  float l0, l1, l2, l3, m0, m1, m2, m3;
  lag4(xb, l0, l1, l2, l3);
  lag4(1.0f - xb, m0, m1, m2, m3);

  v2f v2reg[4];                           // plane-1 (V2) values, kept in regs
#pragma unroll
  for (int q = 0; q < 4; ++q) {
    int j = tid + 256 * q;       // k2
    float2 f = fhat[(size_t)b * 1024 + j];
    int bin = j ^ 512;
    int binp = 1023 - bin;
    float4 cv = ((const float4*)cn4)[bin];
    float4 cw = ((const float4*)cn4)[binp];
    float c  = l0 * cv.x + l1 * cv.y + l2 * cv.z + l3 * cv.w;
    float cp = m0 * cw.x + m1 * cw.y + m2 * cw.z + m3 * cw.w;
    float hf = 1.0f - 0.5f * c;
    float hp = 1.0f - 0.5f * cp;
    int tt = (bin << 10) | b;
    float freq = (float)tt * (1.0f / 1048576.0f) - 0.5f;
    v2f fpm = v2(freq, -freq);           // .x: +freq terms (d), .y: -freq (e)
    v2f A0 = fpm - sp(om0), A1 = fpm - sp(om1), A2v = fpm - sp(om2);
    v2f D0 = A0 * A0, D1 = A1 * A1, D2 = A2v * A2v;
    // plane 0: V0 + i*V1
    v2f DA = pkfma(sp(ALPHA_F), D0 + D1, sp(1.0f));
    v2f DB = pkfma(sp(ALPHA_F), D2, DA);
    float r0 = hf * frcp(DA.x), r0n = hp * frcp(DA.y);
    float r1 = hf * frcp(DB.x), r1n = hp * frcp(DB.y);
    float Rr = 0.5f * (r0 + r0n), Ri = 0.5f * (r1 + r1n);
    A[lpad2(j)] = cmul(v2(f.x, f.y), v2(Rr, Ri));
    // plane 1: V2 (real filter)
    v2f DC = pkfma(sp(ALPHA_F), D1 + D2, sp(1.0f));
    float r2 = hf * frcp(DC.x), r2n = hp * frcp(DC.y);
    float Rr2 = 0.5f * (r2 + r2n);
    v2reg[q] = v2(f.x, f.y) * sp(Rr2);
  }
  __syncthreads();
  fft1024p<1>(A, B);

  // output twiddle by recurrence: z(q) = b*(tid+256q)*2^-19, step b/2048
  float sa, ca, ss, cs;
  sincospif((float)(b * tid) * (2.0f / 1048576.0f), &sa, &ca);
  sincospif((float)b * (1.0f / 2048.0f), &ss, &cs);
  const v2f Einit = v2(ca, sa);
  const v2f S = v2(cs, ss);

  v2f E = Einit;
#pragma unroll
  for (int q = 0; q < 4; ++q) {
    int m1i = tid + 256 * q;
    v2f v = B[lpad2(m1i)];
    v2f o = cmul(v, E);
    ws0[(size_t)m1i * 1024 + b] = make_float2(o.x, o.y);
    E = cmul(E, S);
    A[lpad2(m1i)] = v2reg[q];    // rebuild input for FFT 2 (safe: fft1's final
  }                              // barrier already drained all A-reads)
  __syncthreads();
  fft1024p<1>(A, B);

  E = Einit;
#pragma unroll
  for (int q = 0; q < 4; ++q) {
    int m1i = tid + 256 * q;
    v2f v = B[lpad2(m1i)];
    v2f o = cmul(v, E);
    ws0[1048576 + (size_t)m1i * 1024 + b] = make_float2(o.x, o.y);
    E = cmul(E, S);
  }
}

// ---------------- inverse passB: pk=0 -> out0=Re,out1=Im ; pk=1 -> out2=Re --
__global__ __launch_bounds__(256) void k_inv_B2(const float2* __restrict__ ws0,
                                                float* __restrict__ out)
{
  __shared__ __align__(16) v2f A[PADN2], B[PADN2];
  const int pk = blockIdx.x >> 10;
  const int b = swz(blockIdx.x & 1023);   // m1
  const int tid = threadIdx.x;
#pragma unroll
  for (int q = 0; q < 4; ++q) {
    int j = tid + 256 * q;       // contiguous read of row m1=b
    A[lpad2(j)] = ((const v2f*)ws0)[(size_t)pk * 1048576 + (size_t)b * 1024 + j];
  }
  __syncthreads();
  fft1024p<1>(A, B);
  const float sc = 1.0f / 1048576.0f;
#pragma unroll
  for (int q = 0; q < 4; ++q) {
    int m2 = tid + 256 * q;
    v2f v = B[lpad2(m2)];
    if (pk == 0) {
      out[(size_t)m2 * 1024 + b]           = v.x * sc;   // imf0
      out[1048576 + (size_t)m2 * 1024 + b] = v.y * sc;   // imf1
    } else {
      out[2097152 + (size_t)m2 * 1024 + b] = v.x * sc;   // imf2
    }
  }
}

// ---------------- host launch ----------------
extern "C" void kernel_launch(void* const* d_in, const int* in_sizes, int n_in,
                              void* d_out, int out_size, void* d_ws, size_t ws_size,
                              hipStream_t stream)
{
  (void)in_sizes; (void)n_in; (void)out_size; (void)ws_size;
  const float* x       = (const float*)d_in[0];
  const float* om_init = (const float*)d_in[1];
  float* out = (float*)d_out;

  char* w = (char*)d_ws;
  const size_t MB = 1024ull * 1024ull;
  float2* fhat     = (float2*)(w);
  float*  ET       = (float*)(w + 8 * MB);
  double* W4       = (double*)(w + 12 * MB);            // 4096 doubles (32 KB)
  float*  ckeepN   = (float*)(w + 12 * MB + 32 * 1024); // 4096 floats (16 KB)
  float*  omegaF   = (float*)(w + 12 * MB + 48 * 1024);
  float2* scratch  = (float2*)(w + 16 * MB);            // 2 x 8 MB

  k_fwd_passA<<<512, 256, 0, stream>>>(x, scratch);
  k_fwd_passB<<<1024, 256, 0, stream>>>(scratch, fhat, ET);
  k_moments<<<1024, 256, 0, stream>>>(ET, W4);
  k_solve<<<1, 1024, 0, stream>>>(W4, om_init, ckeepN, omegaF);
  k_inv_A2<<<1024, 256, 0, stream>>>(fhat, ckeepN, omegaF, scratch);
  k_inv_B2<<<2048, 256, 0, stream>>>(scratch, out);
}

// Round 6
// 178.841 us; speedup vs baseline: 1.0631x; 1.0241x over previous
//
#include <hip/hip_runtime.h>
#include <math.h>

// VMD: T = 2^20, K = 3, 50 iterations.
// Round-18: FFT latency-skeleton surgery. Evidence: packed math (R16/R17) cut
// FFT VALU ~40% with ZERO chain-time change => FFT kernels are latency-bound
// on the global->barrier->5x(ds_read->math->ds_write->barrier) skeleton.
//  (1) stage-0 in REGISTERS everywhere: the 4 per-thread global loads ARE
//      X0..X3 of stage 0 (j = tid+256q). Kills input ds_write x4, the load
//      barrier, and stage-0 ds_read x4 -- one LDS round-trip + 1 of 6 barriers
//      per FFT. Same for inv_A2's second FFT (v2reg -> stage0 direct).
//  (2) inv_B2 plane-1 Hermitian pairing: imf2 only needs Re(IFFT(W)) =
//      IFFT(H), H(k)=(W(k)+conj(W(-k)))/2; pack H_b0 + i*H_b1 -> ONE IFFT
//      gives two output rows (Re/Im). pk1 blocks 1024 -> 512 (-512 FFTs).
// k_solve untouched (R15 plateau).
// Workspace (~40 MB of ~256 MB):
//   [0,8MB)   f_hat (float2, s-layout: s = k1*1024+k2, t(s) = ((k2^512)<<10)|k1)
//   [8,12MB)  ET = |f_hat|^2 transposed: ET[k2*1024 + k1] (float)
//   [12MB..)  W f64[1024*4]; ckeepN float[4096]; omegaF float[4]
//   [16,32MB) scratch (2 x 8MB float2) -- FFT intermediates

#define ALPHA_F 2000.0f
#define TAU_F   1e-7f

static __device__ __forceinline__ int lpad2(int i) { return i + (i >> 4); }
static __device__ __forceinline__ int swz(int i)  { return ((i & 7) << 7) | (i >> 3); }
static __device__ __forceinline__ int swzA(int i) { return ((i & 7) << 6) | (i >> 3); }
static __device__ __forceinline__ float frcp(float x) { return __builtin_amdgcn_rcpf(x); }

typedef float v2f __attribute__((ext_vector_type(2)));
static __device__ __forceinline__ v2f sp(float s) { v2f r; r.x = s; r.y = s; return r; }
static __device__ __forceinline__ v2f v2(float a, float b) { v2f r; r.x = a; r.y = b; return r; }
static __device__ __forceinline__ v2f pkfma(v2f a, v2f b, v2f c)
{ return __builtin_elementwise_fma(a, b, c); }
// complex mul: (a.x w.x - a.y w.y, a.x w.y + a.y w.x)
static __device__ __forceinline__ v2f cmul(v2f a, v2f w)
{
  v2f t = a * sp(w.x);
  v2f s = v2(-a.y, a.x);
  return pkfma(s, sp(w.y), t);
}
static __device__ __forceinline__ v2f cmulrr(v2f a, float wr, float wi)
{
  v2f t = a * sp(wr);
  v2f s = v2(-a.y, a.x);
  return pkfma(s, sp(wi), t);
}

#define PADN2 1088

// ---------------- DPP reductions (VALU pipe only) ----------------
template<int CTRL>
static __device__ __forceinline__ float dpp_addf(float v)
{
  int r = __builtin_amdgcn_update_dpp(0, __float_as_int(v), CTRL, 0xf, 0xf, true);
  return v + __int_as_float(r);
}
static __device__ __forceinline__ float wave64_sum(float v)
{
  v = dpp_addf<0x111>(v);   // row_shr:1
  v = dpp_addf<0x112>(v);   // row_shr:2
  v = dpp_addf<0x114>(v);   // row_shr:4
  v = dpp_addf<0x118>(v);   // row_shr:8
  v = dpp_addf<0x142>(v);   // row_bcast:15
  v = dpp_addf<0x143>(v);   // row_bcast:31 -> lane 63 = full sum
  return v;
}
static __device__ __forceinline__ float row16_sum(float v)
{
  v = dpp_addf<0x111>(v);
  v = dpp_addf<0x112>(v);
  v = dpp_addf<0x114>(v);
  v = dpp_addf<0x118>(v);   // lane 15 of each 16-lane row = row sum
  return v;
}
static __device__ __forceinline__ float rdlane(float v, int l)
{
  return __int_as_float(__builtin_amdgcn_readlane(__float_as_int(v), l));
}

// ---------------- 1024-point radix-4 Stockham FFT -------------------------
// Stage 0 computed in REGISTERS from the caller's 4 loaded values
// (X[q] = input[tid + 256 q]); stages 1..4 via LDS with inline twiddles.
// Result lands in B. 5 barriers total (was 6 + load barrier).
template<int SIGN>   // -1 = forward, +1 = inverse (unscaled)
static __device__ void fft1024p_reg(v2f X0, v2f X1, v2f X2, v2f X3,
                                    v2f* A, v2f* B)
{
  const int u = threadIdx.x;
  // ---- stage 0 (twiddle-free), registers -> B ----
  {
    v2f t0 = X0 + X2, t1 = X0 - X2, t2 = X1 + X3, t3 = X1 - X3;
    v2f o0 = t0 + t2, o2 = t0 - t2;
    v2f ns3 = v2(t3.y, -t3.x);
    v2f o1, o3;
    if (SIGN < 0) { o1 = t1 + ns3; o3 = t1 - ns3; }
    else          { o1 = t1 - ns3; o3 = t1 + ns3; }
    const int base = u << 2;
    B[lpad2(base    )] = o0; B[lpad2(base + 1)] = o1;
    B[lpad2(base + 2)] = o2; B[lpad2(base + 3)] = o3;
    __syncthreads();
  }
  // ---- stages 1..4: inline twiddles ----
#pragma unroll
  for (int st = 1; st < 5; ++st) {
    v2f *in  = (st & 1) ? B : A;
    v2f *out = (st & 1) ? A : B;
    const int quarter = 1 << (2 * st);
    const int p = u & (quarter - 1);
    const int g = u >> (2 * st);

    float sw, cw;
    sincospif((float)(2 * p) * (1.0f / (float)(4 << (2 * st))), &sw, &cw);
    const float w1r = cw, w1i = (SIGN < 0) ? -sw : sw;
    const float w2r = w1r * w1r - w1i * w1i, w2i = 2.0f * w1r * w1i;
    const float w3r = w2r * w1r - w2i * w1i, w3i = w2r * w1i + w2i * w1r;

    v2f Y0 = in[lpad2(u)], Y1 = in[lpad2(u + 256)];
    v2f Y2 = in[lpad2(u + 512)], Y3 = in[lpad2(u + 768)];

    v2f y1 = cmulrr(Y1, w1r, w1i), y2 = cmulrr(Y2, w2r, w2i),
        y3 = cmulrr(Y3, w3r, w3i);

    v2f t0 = Y0 + y2, t1 = Y0 - y2, t2 = y1 + y3, t3 = y1 - y3;
    v2f o0 = t0 + t2, o2 = t0 - t2;
    v2f ns3 = v2(t3.y, -t3.x);
    v2f o1, o3;
    if (SIGN < 0) { o1 = t1 + ns3; o3 = t1 - ns3; }
    else          { o1 = t1 - ns3; o3 = t1 + ns3; }

    const int base = (g << (2 * st + 2)) + p;
    out[lpad2(base              )] = o0;
    out[lpad2(base +     quarter)] = o1;
    out[lpad2(base + 2 * quarter)] = o2;
    out[lpad2(base + 3 * quarter)] = o3;
    __syncthreads();
  }
}

// ---------------- forward passA: packed-real, 2 columns per block ----------
// z_j = x[j][2p] + i*x[j][2p+1]; after FFT, Hermitian split recovers both
// column spectra; twiddle each (recurrence); one float4 store writes both.
__global__ __launch_bounds__(256) void k_fwd_passA(const float* __restrict__ x,
                                                   float2* __restrict__ ws0)
{
  __shared__ __align__(16) v2f A[PADN2], B[PADN2];
  const int p = swzA(blockIdx.x);     // 512 blocks; column pair (2p, 2p+1)
  const int tid = threadIdx.x;
  const int c0 = 2 * p;
  v2f X[4];
#pragma unroll
  for (int q = 0; q < 4; ++q)
    X[q] = ((const v2f*)x)[(size_t)(tid + 256 * q) * 512 + p];
  fft1024p_reg<-1>(X[0], X[1], X[2], X[3], A, B);

  // output twiddles by recurrence: step c0/2048 (and (c0+1)/2048)
  float sa, ca, sb, cb, ssa, cca, ssb, ccb;
  sincospif((float)(c0 * tid) * (2.0f / 1048576.0f), &sa, &ca);
  sincospif((float)((c0 + 1) * tid) * (2.0f / 1048576.0f), &sb, &cb);
  sincospif((float)c0 * (1.0f / 2048.0f), &ssa, &cca);
  sincospif((float)(c0 + 1) * (1.0f / 2048.0f), &ssb, &ccb);
  v2f E0 = v2(ca, -sa), E1 = v2(cb, -sb);
  const v2f S0 = v2(cca, -ssa), S1 = v2(ccb, -ssb);
#pragma unroll
  for (int q = 0; q < 4; ++q) {
    int k = tid + 256 * q;
    int kk = (1024 - k) & 1023;
    v2f Z = B[lpad2(k)];
    v2f Wv = B[lpad2(kk)];
    // X0 = (Z + conj(W))/2 ; X1 = (Z - conj(W))/(2i)
    float X0r = 0.5f * (Z.x + Wv.x), X0i = 0.5f * (Z.y - Wv.y);
    float X1r = 0.5f * (Z.y + Wv.y), X1i = 0.5f * (Wv.x - Z.x);
    v2f o01 = cmul(v2(X0r, X0i), E0);
    v2f o23 = cmul(v2(X1r, X1i), E1);
    float4 o = make_float4(o01.x, o01.y, o23.x, o23.y);
    ((float4*)ws0)[(size_t)k * 512 + p] = o;   // ws0[k*1024 + c0 .. c0+1]
    E0 = cmul(E0, S0); E1 = cmul(E1, S1);
  }
}

// ---------------- forward passB: contiguous reads; stores fhat + E^T --------
__global__ __launch_bounds__(256) void k_fwd_passB(const float2* __restrict__ ws0,
                                                   float2* __restrict__ fhat,
                                                   float* __restrict__ ET)
{
  __shared__ __align__(16) v2f A[PADN2], B[PADN2];
  const int b = swz(blockIdx.x);   // k1
  const int tid = threadIdx.x;
  v2f X[4];
#pragma unroll
  for (int q = 0; q < 4; ++q)
    X[q] = ((const v2f*)ws0)[(size_t)b * 1024 + tid + 256 * q];
  fft1024p_reg<-1>(X[0], X[1], X[2], X[3], A, B);
#pragma unroll
  for (int q = 0; q < 4; ++q) {
    int k2 = tid + 256 * q;
    v2f v = B[lpad2(k2)];
    fhat[(size_t)b * 1024 + k2] = make_float2(v.x, v.y);
    ET[(size_t)k2 * 1024 + b] = v.x * v.x + v.y * v.y;  // strided store (cheap)
  }
}

// ---------------- Lagrange basis on nodes x = {0, 1/3, 2/3, 1} --------------
static __device__ __forceinline__ void lag4(float x, float& l0, float& l1,
                                            float& l2, float& l3)
{
  float m0 = x, m1 = x - (1.0f / 3.0f), m2 = x - (2.0f / 3.0f), m3 = x - 1.0f;
  l0 = -4.5f * m1 * m2 * m3;
  l1 = 13.5f * m0 * m2 * m3;
  l2 = -13.5f * m0 * m1 * m3;
  l3 =  4.5f * m0 * m1 * m2;
}

// ---------------- bin weights from E^T (fully contiguous reads) -------------
__global__ __launch_bounds__(256) void k_moments(const float* __restrict__ ET,
                                                 double* __restrict__ W)
{
  __shared__ double red[4 * 4];
  const int B = blockIdx.x;        // bin
  const int k2 = B ^ 512;
  const int tid = threadIdx.x;
  double a0 = 0, a1 = 0, a2 = 0, a3 = 0;
#pragma unroll
  for (int q = 0; q < 4; ++q) {
    int k1 = tid + 256 * q;
    float e = ET[(size_t)k2 * 1024 + k1];   // contiguous
    float l0, l1, l2, l3;
    lag4((float)k1 * (1.0f / 1024.0f), l0, l1, l2, l3);
    a0 += (double)(e * l0); a1 += (double)(e * l1);
    a2 += (double)(e * l2); a3 += (double)(e * l3);
  }
  const int lane = tid & 63, wv = tid >> 6;       // 4 waves
  double pv[4] = { a0, a1, a2, a3 };
#pragma unroll
  for (int j = 0; j < 4; ++j) {
    double v = pv[j];
    for (int off = 32; off; off >>= 1) v += __shfl_down(v, off, 64);
    if (lane == 0) red[wv * 4 + j] = v;
  }
  __syncthreads();
  if (tid < 4)
    W[B * 4 + tid] = red[tid] + red[4 + tid] + red[8 + tid] + red[12 + tid];
}

// ---------------- the whole solve loop in ONE workgroup ---------------------
// 1024 threads (16 waves); thread t owns bin t (4 cubic nodes, as 2 packed
// pairs). ONE barrier per iteration (red[] double-buffered). Packed fp32 math.
__global__ __launch_bounds__(1024) void k_solve(
    const double* __restrict__ W4, const float* __restrict__ omega_init,
    float* __restrict__ ckeepN, float* __restrict__ omegaF)
{
  __shared__ float red[2][6 * 16];   // [buf][slot*16 + wave]
  const int t = threadIdx.x;
  const int lane = t & 63, wv = t >> 6;    // 16 waves

  float Wsc[4], fsc[4];
#pragma unroll
  for (int e = 0; e < 4; ++e) {
    Wsc[e] = (float)W4[t * 4 + e];
    fsc[e] = (float)((double)t / 1024.0 + (double)e / 3072.0 - 0.5);
  }
  const v2f frP = v2(fsc[0], fsc[1]), frQ = v2(fsc[2], fsc[3]);
  const v2f WrP = v2(Wsc[0], Wsc[1]), WrQ = v2(Wsc[2], Wsc[3]);
  const v2f WfP = WrP * frP,          WfQ = WrQ * frQ;
  v2f cnrP = sp(0.0f), cnrQ = sp(0.0f);

  float om0 = omega_init[0], om1 = omega_init[1], om2 = omega_init[2];

#pragma unroll 1
  for (int it = 0; it < 49; ++it) {        // n = 0 .. 48
    float* rb = red[it & 1];
    v2f p0 = sp(0.f), p1 = sp(0.f), p2 = sp(0.f),
        p3 = sp(0.f), p4 = sp(0.f), p5 = sp(0.f);

    auto node_pair = [&](const v2f fv, const v2f Wrv, const v2f Wfv, v2f& cnv) {
      v2f a0 = fv - sp(om0), a1 = fv - sp(om1), a2 = fv - sp(om2);
      v2f d0 = a0 * a0, d1 = a1 * a1, d2 = a2 * a2;
      v2f s01 = d0 + d1, s12 = d1 + d2;
      v2f dA = pkfma(sp(ALPHA_F), s01, sp(1.0f));   // 1 + a(d0+d1)
      v2f dC = pkfma(sp(ALPHA_F), s12, sp(1.0f));   // 1 + a(d1+d2)
      v2f dB = pkfma(sp(ALPHA_F), d2, dA);          // 1 + a(d0+d1+d2)
      v2f AB = dA * dB, BC = dB * dC, AC = dA * dC;
      v2f ABC = AB * dC;
      v2f r = v2(frcp(ABC.x), frcp(ABC.y));         // scalar rcps
      v2f w0 = BC * r, w1 = AC * r, w2 = AB * r;
      v2f hf = pkfma(sp(-0.5f), cnv, sp(1.0f));
      v2f g = hf * hf;
      v2f gw0 = g * (w0 * w0), gw1 = g * (w1 * w1), gw2 = g * (w2 * w2);
      p0 = pkfma(Wfv, gw0, p0); p1 = pkfma(Wfv, gw1, p1); p2 = pkfma(Wfv, gw2, p2);
      p3 = pkfma(Wrv, gw0, p3); p4 = pkfma(Wrv, gw1, p4); p5 = pkfma(Wrv, gw2, p5);
      v2f S = (w0 + w1) + w2;
      cnv = pkfma(sp(TAU_F), pkfma(S, hf, sp(-1.0f)), cnv);
    };
    node_pair(frP, WrP, WfP, cnrP);
    node_pair(frQ, WrQ, WfQ, cnrQ);

    float q0 = p0.x + p0.y, q1 = p1.x + p1.y, q2 = p2.x + p2.y;
    float q3 = p3.x + p3.y, q4 = p4.x + p4.y, q5 = p5.x + p5.y;

    q0 = wave64_sum(q0); q1 = wave64_sum(q1); q2 = wave64_sum(q2);
    q3 = wave64_sum(q3); q4 = wave64_sum(q4); q5 = wave64_sum(q5);
    if (lane == 63) {
      rb[0 * 16 + wv] = q0; rb[1 * 16 + wv] = q1; rb[2 * 16 + wv] = q2;
      rb[3 * 16 + wv] = q3; rb[4 * 16 + wv] = q4; rb[5 * 16 + wv] = q5;
    }
    __syncthreads();                 // the ONLY barrier in the iteration
    // stage 2, redundantly per wave: slots 0..3 from v1, slots 4..5 from v2
    float v1 = rb[lane];                     // red[slot(lane>>4)*16 + (lane&15)]
    float v2_ = rb[64 + (lane & 31)];        // slots 4,5 (lanes 32..63 dup)
    v1 = row16_sum(v1);
    v2_ = row16_sum(v2_);
    float n0 = rdlane(v1, 15), n1 = rdlane(v1, 31), n2 = rdlane(v1, 47);
    float e0 = rdlane(v1, 63), e1 = rdlane(v2_, 15), e2 = rdlane(v2_, 31);
    om0 = n0 * frcp(e0);
    om1 = n1 * frcp(e1);
    om2 = n2 * frcp(e2);
  }

  // entry state of n = 49 (same layout as before: node id = bin*4 + j)
  ((float4*)ckeepN)[t] = make_float4(cnrP.x, cnrP.y, cnrQ.x, cnrQ.y);
  if (t == 0) { omegaF[0] = om0; omegaF[1] = om1; omegaF[2] = om2; }
}

// ---------------- inverse passA (FUSED): both planes per block --------------
// Block b: loads fhat row once into regs, builds V0+i*V1 (plane 0) -> FFT ->
// store; second FFT fed from v2reg via register stage-0. Filter math
// formula-identical to the split version; shared c/cp/D0..D2.
__global__ __launch_bounds__(256) void k_inv_A2(
    const float2* __restrict__ fhat, const float* __restrict__ ckeepN,
    const float* __restrict__ omegaF, float2* __restrict__ ws0)
{
  __shared__ __align__(16) v2f A[PADN2], B[PADN2];
  __shared__ float cn4[4096];
  __shared__ float som[3];
  const int tid = threadIdx.x;
  const int b = swz(blockIdx.x);          // 1024 blocks; k1 of s-layout
  for (int i = tid; i < 1024; i += 256)
    ((float4*)cn4)[i] = ((const float4*)ckeepN)[i];
  if (tid == 0) { som[0] = omegaF[0]; som[1] = omegaF[1]; som[2] = omegaF[2]; }
  __syncthreads();
  const float om0 = som[0], om1 = som[1], om2 = som[2];
  const float xb = (float)b * (1.0f / 1024.0f);
  float l0, l1, l2, l3, m0, m1, m2, m3;
  lag4(xb, l0, l1, l2, l3);
  lag4(1.0f - xb, m0, m1, m2, m3);

  v2f X[4];                               // plane-0 values
  v2f v2reg[4];                           // plane-1 (V2) values, kept in regs
#pragma unroll
  for (int q = 0; q < 4; ++q) {
    int j = tid + 256 * q;       // k2
    float2 f = fhat[(size_t)b * 1024 + j];
    int bin = j ^ 512;
    int binp = 1023 - bin;
    float4 cv = ((const float4*)cn4)[bin];
    float4 cw = ((const float4*)cn4)[binp];
    float c  = l0 * cv.x + l1 * cv.y + l2 * cv.z + l3 * cv.w;
    float cp = m0 * cw.x + m1 * cw.y + m2 * cw.z + m3 * cw.w;
    float hf = 1.0f - 0.5f * c;
    float hp = 1.0f - 0.5f * cp;
    int tt = (bin << 10) | b;
    float freq = (float)tt * (1.0f / 1048576.0f) - 0.5f;
    v2f fpm = v2(freq, -freq);           // .x: +freq terms (d), .y: -freq (e)
    v2f A0 = fpm - sp(om0), A1 = fpm - sp(om1), A2v = fpm - sp(om2);
    v2f D0 = A0 * A0, D1 = A1 * A1, D2 = A2v * A2v;
    // plane 0: V0 + i*V1
    v2f DA = pkfma(sp(ALPHA_F), D0 + D1, sp(1.0f));
    v2f DB = pkfma(sp(ALPHA_F), D2, DA);
    float r0 = hf * frcp(DA.x), r0n = hp * frcp(DA.y);
    float r1 = hf * frcp(DB.x), r1n = hp * frcp(DB.y);
    float Rr = 0.5f * (r0 + r0n), Ri = 0.5f * (r1 + r1n);
    X[q] = cmul(v2(f.x, f.y), v2(Rr, Ri));
    // plane 1: V2 (real filter)
    v2f DC = pkfma(sp(ALPHA_F), D1 + D2, sp(1.0f));
    float r2 = hf * frcp(DC.x), r2n = hp * frcp(DC.y);
    float Rr2 = 0.5f * (r2 + r2n);
    v2reg[q] = v2(f.x, f.y) * sp(Rr2);
  }
  fft1024p_reg<1>(X[0], X[1], X[2], X[3], A, B);

  // output twiddle by recurrence: z(q) = b*(tid+256q)*2^-19, step b/2048
  float sa, ca, ss, cs;
  sincospif((float)(b * tid) * (2.0f / 1048576.0f), &sa, &ca);
  sincospif((float)b * (1.0f / 2048.0f), &ss, &cs);
  const v2f Einit = v2(ca, sa);
  const v2f S = v2(cs, ss);

  v2f E = Einit;
#pragma unroll
  for (int q = 0; q < 4; ++q) {
    int m1i = tid + 256 * q;
    v2f v = B[lpad2(m1i)];
    v2f o = cmul(v, E);
    ws0[(size_t)m1i * 1024 + b] = make_float2(o.x, o.y);
    E = cmul(E, S);
  }
  __syncthreads();   // all B-reads done before fft2's stage-0 overwrites B
  fft1024p_reg<1>(v2reg[0], v2reg[1], v2reg[2], v2reg[3], A, B);

  E = Einit;
#pragma unroll
  for (int q = 0; q < 4; ++q) {
    int m1i = tid + 256 * q;
    v2f v = B[lpad2(m1i)];
    v2f o = cmul(v, E);
    ws0[1048576 + (size_t)m1i * 1024 + b] = make_float2(o.x, o.y);
    E = cmul(E, S);
  }
}

// ---------------- inverse passB --------------------------------------------
// blocks [0,1024):  plane 0 -> out0 = Re, out1 = Im (unchanged)
// blocks [1024,1536): plane 1 PAIRED: rows b0=2s, b1=2s+1 Hermitian-combined
//   Z = H_{b0} + i*H_{b1}, one IFFT -> out2 rows b0 (Re) and b1 (Im).
__global__ __launch_bounds__(256) void k_inv_B2(const float2* __restrict__ ws0,
                                                float* __restrict__ out)
{
  __shared__ __align__(16) v2f A[PADN2], B[PADN2];
  const int tid = threadIdx.x;
  const float sc = 1.0f / 1048576.0f;

  if (blockIdx.x < 1024) {               // ---- plane 0 ----
    const int b = swz(blockIdx.x);       // m1
    v2f X[4];
#pragma unroll
    for (int q = 0; q < 4; ++q)
      X[q] = ((const v2f*)ws0)[(size_t)b * 1024 + tid + 256 * q];
    fft1024p_reg<1>(X[0], X[1], X[2], X[3], A, B);
#pragma unroll
    for (int q = 0; q < 4; ++q) {
      int m2 = tid + 256 * q;
      v2f v = B[lpad2(m2)];
      out[(size_t)m2 * 1024 + b]           = v.x * sc;   // imf0
      out[1048576 + (size_t)m2 * 1024 + b] = v.y * sc;   // imf1
    }
  } else {                               // ---- plane 1, paired rows ----
    const int s = swzA(blockIdx.x - 1024);   // [0,512)
    const int b0 = 2 * s, b1 = 2 * s + 1;
    // stage the two rows: row b0 -> A, row b1 -> B
#pragma unroll
    for (int q = 0; q < 4; ++q) {
      int j = tid + 256 * q;
      A[lpad2(j)] = ((const v2f*)ws0)[1048576 + (size_t)b0 * 1024 + j];
      B[lpad2(j)] = ((const v2f*)ws0)[1048576 + (size_t)b1 * 1024 + j];
    }
    __syncthreads();
    v2f Z[4];
#pragma unroll
    for (int q = 0; q < 4; ++q) {
      int j = tid + 256 * q;
      int mj = (1024 - j) & 1023;
      v2f W0j = A[lpad2(j)], W0m = A[lpad2(mj)];
      v2f W1j = B[lpad2(j)], W1m = B[lpad2(mj)];
      // H = (W(j) + conj(W(mj)))/2 ; Z = H0 + i*H1
      float H0r = 0.5f * (W0j.x + W0m.x), H0i = 0.5f * (W0j.y - W0m.y);
      float H1r = 0.5f * (W1j.x + W1m.x), H1i = 0.5f * (W1j.y - W1m.y);
      Z[q] = v2(H0r - H1i, H0i + H1r);
    }
    __syncthreads();   // all reads of A/B done before stage-0 writes B
    fft1024p_reg<1>(Z[0], Z[1], Z[2], Z[3], A, B);
#pragma unroll
    for (int q = 0; q < 4; ++q) {
      int m2 = tid + 256 * q;
      v2f v = B[lpad2(m2)];
      out[2097152 + (size_t)m2 * 1024 + b0] = v.x * sc;  // imf2 row b0
      out[2097152 + (size_t)m2 * 1024 + b1] = v.y * sc;  // imf2 row b1
    }
  }
}

// ---------------- host launch ----------------
extern "C" void kernel_launch(void* const* d_in, const int* in_sizes, int n_in,
                              void* d_out, int out_size, void* d_ws, size_t ws_size,
                              hipStream_t stream)
{
  (void)in_sizes; (void)n_in; (void)out_size; (void)ws_size;
  const float* x       = (const float*)d_in[0];
  const float* om_init = (const float*)d_in[1];
  float* out = (float*)d_out;

  char* w = (char*)d_ws;
  const size_t MB = 1024ull * 1024ull;
  float2* fhat     = (float2*)(w);
  float*  ET       = (float*)(w + 8 * MB);
  double* W4       = (double*)(w + 12 * MB);            // 4096 doubles (32 KB)
  float*  ckeepN   = (float*)(w + 12 * MB + 32 * 1024); // 4096 floats (16 KB)
  float*  omegaF   = (float*)(w + 12 * MB + 48 * 1024);
  float2* scratch  = (float2*)(w + 16 * MB);            // 2 x 8 MB

  k_fwd_passA<<<512, 256, 0, stream>>>(x, scratch);
  k_fwd_passB<<<1024, 256, 0, stream>>>(scratch, fhat, ET);
  k_moments<<<1024, 256, 0, stream>>>(ET, W4);
  k_solve<<<1, 1024, 0, stream>>>(W4, om_init, ckeepN, omegaF);
  k_inv_A2<<<1024, 256, 0, stream>>>(fhat, ckeepN, omegaF, scratch);
  k_inv_B2<<<1536, 256, 0, stream>>>(scratch, out);
}

// Round 7
// 170.300 us; speedup vs baseline: 1.1164x; 1.0502x over previous
//
#include <hip/hip_runtime.h>
#include <math.h>

// VMD: T = 2^20, K = 3, 50 iterations.
// Round-19:
//  (1) k_solve: 512 threads x 8 nodes (4 v2f pairs). The DPP reduction
//      (36 DPP) + stage-2 (~22 ops) is per-WAVE fixed cost: halving waves
//      halves total reduction instructions while inner math is constant.
//      + paired-reciprocal trick (r=rcp(x*y): 1/x=r*y, 1/y=r*x) halves rcps.
//      + stage-2 = ONE ds_read + row8_sum (6 slots x 8 waves = 48 lanes).
//  (2) k_inv_A2: the two per-block FFTs INTERLEAVED in one pass (4 LDS bufs):
//      5 barrier phases for both (was 10), one sincospif/stage (was 2), one
//      E-recurrence; per-phase ILP doubles. cn4/som LDS staging dropped
//      (ckeepN 16KB is L2-resident; direct coalesced float4 reads).
// Workspace (~40 MB of ~256 MB):
//   [0,8MB)   f_hat (float2, s-layout: s = k1*1024+k2, t(s) = ((k2^512)<<10)|k1)
//   [8,12MB)  ET = |f_hat|^2 transposed: ET[k2*1024 + k1] (float)
//   [12MB..)  W f64[1024*4]; ckeepN float[4096]; omegaF float[4]
//   [16,32MB) scratch (2 x 8MB float2) -- FFT intermediates

#define ALPHA_F 2000.0f
#define TAU_F   1e-7f

static __device__ __forceinline__ int lpad2(int i) { return i + (i >> 4); }
static __device__ __forceinline__ int swz(int i)  { return ((i & 7) << 7) | (i >> 3); }
static __device__ __forceinline__ int swzA(int i) { return ((i & 7) << 6) | (i >> 3); }
static __device__ __forceinline__ float frcp(float x) { return __builtin_amdgcn_rcpf(x); }

typedef float v2f __attribute__((ext_vector_type(2)));
static __device__ __forceinline__ v2f sp(float s) { v2f r; r.x = s; r.y = s; return r; }
static __device__ __forceinline__ v2f v2(float a, float b) { v2f r; r.x = a; r.y = b; return r; }
static __device__ __forceinline__ v2f pkfma(v2f a, v2f b, v2f c)
{ return __builtin_elementwise_fma(a, b, c); }
// complex mul: (a.x w.x - a.y w.y, a.x w.y + a.y w.x)
static __device__ __forceinline__ v2f cmul(v2f a, v2f w)
{
  v2f t = a * sp(w.x);
  v2f s = v2(-a.y, a.x);
  return pkfma(s, sp(w.y), t);
}
static __device__ __forceinline__ v2f cmulrr(v2f a, float wr, float wi)
{
  v2f t = a * sp(wr);
  v2f s = v2(-a.y, a.x);
  return pkfma(s, sp(wi), t);
}

#define PADN2 1088

// ---------------- DPP reductions (VALU pipe only) ----------------
template<int CTRL>
static __device__ __forceinline__ float dpp_addf(float v)
{
  int r = __builtin_amdgcn_update_dpp(0, __float_as_int(v), CTRL, 0xf, 0xf, true);
  return v + __int_as_float(r);
}
static __device__ __forceinline__ float wave64_sum(float v)
{
  v = dpp_addf<0x111>(v);   // row_shr:1
  v = dpp_addf<0x112>(v);   // row_shr:2
  v = dpp_addf<0x114>(v);   // row_shr:4
  v = dpp_addf<0x118>(v);   // row_shr:8
  v = dpp_addf<0x142>(v);   // row_bcast:15
  v = dpp_addf<0x143>(v);   // row_bcast:31 -> lane 63 = full sum
  return v;
}
static __device__ __forceinline__ float row8_sum(float v)
{
  v = dpp_addf<0x111>(v);
  v = dpp_addf<0x112>(v);
  v = dpp_addf<0x114>(v);   // lane 7 (mod 8 within row16) = 8-group sum
  return v;
}
static __device__ __forceinline__ float rdlane(float v, int l)
{
  return __int_as_float(__builtin_amdgcn_readlane(__float_as_int(v), l));
}

// ---------------- radix-4 butterfly helper ---------------------------------
template<int SIGN>
static __device__ __forceinline__ void bfly4(v2f Y0, v2f Y1, v2f Y2, v2f Y3,
    float w1r, float w1i, float w2r, float w2i, float w3r, float w3i,
    v2f& o0, v2f& o1, v2f& o2, v2f& o3)
{
  v2f y1 = cmulrr(Y1, w1r, w1i), y2 = cmulrr(Y2, w2r, w2i),
      y3 = cmulrr(Y3, w3r, w3i);
  v2f t0 = Y0 + y2, t1 = Y0 - y2, t2 = y1 + y3, t3 = y1 - y3;
  o0 = t0 + t2; o2 = t0 - t2;
  v2f ns3 = v2(t3.y, -t3.x);
  if (SIGN < 0) { o1 = t1 + ns3; o3 = t1 - ns3; }
  else          { o1 = t1 - ns3; o3 = t1 + ns3; }
}
template<int SIGN>
static __device__ __forceinline__ void bfly4_nt(v2f X0, v2f X1, v2f X2, v2f X3,
    v2f& o0, v2f& o1, v2f& o2, v2f& o3)   // twiddle-free (stage 0)
{
  v2f t0 = X0 + X2, t1 = X0 - X2, t2 = X1 + X3, t3 = X1 - X3;
  o0 = t0 + t2; o2 = t0 - t2;
  v2f ns3 = v2(t3.y, -t3.x);
  if (SIGN < 0) { o1 = t1 + ns3; o3 = t1 - ns3; }
  else          { o1 = t1 - ns3; o3 = t1 + ns3; }
}

// ---------------- 1024-point radix-4 Stockham FFT -------------------------
// Stage 0 in registers from the caller's 4 loaded values (X[q] at tid+256q);
// stages 1..4 via LDS with inline twiddles. Result in B. 5 barriers.
template<int SIGN>   // -1 = forward, +1 = inverse (unscaled)
static __device__ void fft1024p_reg(v2f X0, v2f X1, v2f X2, v2f X3,
                                    v2f* A, v2f* B)
{
  const int u = threadIdx.x;
  {
    v2f o0, o1, o2, o3;
    bfly4_nt<SIGN>(X0, X1, X2, X3, o0, o1, o2, o3);
    const int base = u << 2;
    B[lpad2(base    )] = o0; B[lpad2(base + 1)] = o1;
    B[lpad2(base + 2)] = o2; B[lpad2(base + 3)] = o3;
    __syncthreads();
  }
#pragma unroll
  for (int st = 1; st < 5; ++st) {
    v2f *in  = (st & 1) ? B : A;
    v2f *out = (st & 1) ? A : B;
    const int quarter = 1 << (2 * st);
    const int p = u & (quarter - 1);
    const int g = u >> (2 * st);

    float sw, cw;
    sincospif((float)(2 * p) * (1.0f / (float)(4 << (2 * st))), &sw, &cw);
    const float w1r = cw, w1i = (SIGN < 0) ? -sw : sw;
    const float w2r = w1r * w1r - w1i * w1i, w2i = 2.0f * w1r * w1i;
    const float w3r = w2r * w1r - w2i * w1i, w3i = w2r * w1i + w2i * w1r;

    v2f o0, o1, o2, o3;
    bfly4<SIGN>(in[lpad2(u)], in[lpad2(u + 256)],
                in[lpad2(u + 512)], in[lpad2(u + 768)],
                w1r, w1i, w2r, w2i, w3r, w3i, o0, o1, o2, o3);

    const int base = (g << (2 * st + 2)) + p;
    out[lpad2(base              )] = o0;
    out[lpad2(base +     quarter)] = o1;
    out[lpad2(base + 2 * quarter)] = o2;
    out[lpad2(base + 3 * quarter)] = o3;
    __syncthreads();
  }
}

// ---- dual: two interleaved 1024-FFTs sharing twiddles & barriers ----------
template<int SIGN>
static __device__ void fft1024p_dual(const v2f X[4], const v2f Y[4],
                                     v2f* A1, v2f* B1, v2f* A2, v2f* B2)
{
  const int u = threadIdx.x;
  {
    v2f o0, o1, o2, o3, p0, p1, p2, p3;
    bfly4_nt<SIGN>(X[0], X[1], X[2], X[3], o0, o1, o2, o3);
    bfly4_nt<SIGN>(Y[0], Y[1], Y[2], Y[3], p0, p1, p2, p3);
    const int base = u << 2;
    B1[lpad2(base    )] = o0; B1[lpad2(base + 1)] = o1;
    B1[lpad2(base + 2)] = o2; B1[lpad2(base + 3)] = o3;
    B2[lpad2(base    )] = p0; B2[lpad2(base + 1)] = p1;
    B2[lpad2(base + 2)] = p2; B2[lpad2(base + 3)] = p3;
    __syncthreads();
  }
#pragma unroll
  for (int st = 1; st < 5; ++st) {
    v2f *in1  = (st & 1) ? B1 : A1, *out1 = (st & 1) ? A1 : B1;
    v2f *in2  = (st & 1) ? B2 : A2, *out2 = (st & 1) ? A2 : B2;
    const int quarter = 1 << (2 * st);
    const int p = u & (quarter - 1);
    const int g = u >> (2 * st);

    float sw, cw;
    sincospif((float)(2 * p) * (1.0f / (float)(4 << (2 * st))), &sw, &cw);
    const float w1r = cw, w1i = (SIGN < 0) ? -sw : sw;
    const float w2r = w1r * w1r - w1i * w1i, w2i = 2.0f * w1r * w1i;
    const float w3r = w2r * w1r - w2i * w1i, w3i = w2r * w1i + w2i * w1r;

    v2f o0, o1, o2, o3, p0, p1, p2, p3;
    bfly4<SIGN>(in1[lpad2(u)], in1[lpad2(u + 256)],
                in1[lpad2(u + 512)], in1[lpad2(u + 768)],
                w1r, w1i, w2r, w2i, w3r, w3i, o0, o1, o2, o3);
    bfly4<SIGN>(in2[lpad2(u)], in2[lpad2(u + 256)],
                in2[lpad2(u + 512)], in2[lpad2(u + 768)],
                w1r, w1i, w2r, w2i, w3r, w3i, p0, p1, p2, p3);

    const int base = (g << (2 * st + 2)) + p;
    out1[lpad2(base              )] = o0;
    out1[lpad2(base +     quarter)] = o1;
    out1[lpad2(base + 2 * quarter)] = o2;
    out1[lpad2(base + 3 * quarter)] = o3;
    out2[lpad2(base              )] = p0;
    out2[lpad2(base +     quarter)] = p1;
    out2[lpad2(base + 2 * quarter)] = p2;
    out2[lpad2(base + 3 * quarter)] = p3;
    __syncthreads();
  }
}

// ---------------- forward passA: packed-real, 2 columns per block ----------
__global__ __launch_bounds__(256) void k_fwd_passA(const float* __restrict__ x,
                                                   float2* __restrict__ ws0)
{
  __shared__ __align__(16) v2f A[PADN2], B[PADN2];
  const int p = swzA(blockIdx.x);     // 512 blocks; column pair (2p, 2p+1)
  const int tid = threadIdx.x;
  const int c0 = 2 * p;
  v2f X[4];
#pragma unroll
  for (int q = 0; q < 4; ++q)
    X[q] = ((const v2f*)x)[(size_t)(tid + 256 * q) * 512 + p];
  fft1024p_reg<-1>(X[0], X[1], X[2], X[3], A, B);

  float sa, ca, sb, cb, ssa, cca, ssb, ccb;
  sincospif((float)(c0 * tid) * (2.0f / 1048576.0f), &sa, &ca);
  sincospif((float)((c0 + 1) * tid) * (2.0f / 1048576.0f), &sb, &cb);
  sincospif((float)c0 * (1.0f / 2048.0f), &ssa, &cca);
  sincospif((float)(c0 + 1) * (1.0f / 2048.0f), &ssb, &ccb);
  v2f E0 = v2(ca, -sa), E1 = v2(cb, -sb);
  const v2f S0 = v2(cca, -ssa), S1 = v2(ccb, -ssb);
#pragma unroll
  for (int q = 0; q < 4; ++q) {
    int k = tid + 256 * q;
    int kk = (1024 - k) & 1023;
    v2f Z = B[lpad2(k)];
    v2f Wv = B[lpad2(kk)];
    float X0r = 0.5f * (Z.x + Wv.x), X0i = 0.5f * (Z.y - Wv.y);
    float X1r = 0.5f * (Z.y + Wv.y), X1i = 0.5f * (Wv.x - Z.x);
    v2f o01 = cmul(v2(X0r, X0i), E0);
    v2f o23 = cmul(v2(X1r, X1i), E1);
    float4 o = make_float4(o01.x, o01.y, o23.x, o23.y);
    ((float4*)ws0)[(size_t)k * 512 + p] = o;   // ws0[k*1024 + c0 .. c0+1]
    E0 = cmul(E0, S0); E1 = cmul(E1, S1);
  }
}

// ---------------- forward passB: contiguous reads; stores fhat + E^T --------
__global__ __launch_bounds__(256) void k_fwd_passB(const float2* __restrict__ ws0,
                                                   float2* __restrict__ fhat,
                                                   float* __restrict__ ET)
{
  __shared__ __align__(16) v2f A[PADN2], B[PADN2];
  const int b = swz(blockIdx.x);   // k1
  const int tid = threadIdx.x;
  v2f X[4];
#pragma unroll
  for (int q = 0; q < 4; ++q)
    X[q] = ((const v2f*)ws0)[(size_t)b * 1024 + tid + 256 * q];
  fft1024p_reg<-1>(X[0], X[1], X[2], X[3], A, B);
#pragma unroll
  for (int q = 0; q < 4; ++q) {
    int k2 = tid + 256 * q;
    v2f v = B[lpad2(k2)];
    fhat[(size_t)b * 1024 + k2] = make_float2(v.x, v.y);
    ET[(size_t)k2 * 1024 + b] = v.x * v.x + v.y * v.y;  // strided store (cheap)
  }
}

// ---------------- Lagrange basis on nodes x = {0, 1/3, 2/3, 1} --------------
static __device__ __forceinline__ void lag4(float x, float& l0, float& l1,
                                            float& l2, float& l3)
{
  float m0 = x, m1 = x - (1.0f / 3.0f), m2 = x - (2.0f / 3.0f), m3 = x - 1.0f;
  l0 = -4.5f * m1 * m2 * m3;
  l1 = 13.5f * m0 * m2 * m3;
  l2 = -13.5f * m0 * m1 * m3;
  l3 =  4.5f * m0 * m1 * m2;
}

// ---------------- bin weights from E^T (fully contiguous reads) -------------
__global__ __launch_bounds__(256) void k_moments(const float* __restrict__ ET,
                                                 double* __restrict__ W)
{
  __shared__ double red[4 * 4];
  const int B = blockIdx.x;        // bin
  const int k2 = B ^ 512;
  const int tid = threadIdx.x;
  double a0 = 0, a1 = 0, a2 = 0, a3 = 0;
#pragma unroll
  for (int q = 0; q < 4; ++q) {
    int k1 = tid + 256 * q;
    float e = ET[(size_t)k2 * 1024 + k1];   // contiguous
    float l0, l1, l2, l3;
    lag4((float)k1 * (1.0f / 1024.0f), l0, l1, l2, l3);
    a0 += (double)(e * l0); a1 += (double)(e * l1);
    a2 += (double)(e * l2); a3 += (double)(e * l3);
  }
  const int lane = tid & 63, wv = tid >> 6;       // 4 waves
  double pv[4] = { a0, a1, a2, a3 };
#pragma unroll
  for (int j = 0; j < 4; ++j) {
    double v = pv[j];
    for (int off = 32; off; off >>= 1) v += __shfl_down(v, off, 64);
    if (lane == 0) red[wv * 4 + j] = v;
  }
  __syncthreads();
  if (tid < 4)
    W[B * 4 + tid] = red[tid] + red[4 + tid] + red[8 + tid] + red[12 + tid];
}

// ---------------- the whole solve loop in ONE workgroup ---------------------
// 512 threads (8 waves); thread t owns bins 2t,2t+1 (8 nodes as 4 v2f pairs).
// Per-wave reduction overhead (36 DPP + stage-2) amortized over 2x nodes.
// ONE barrier/iter (red double-buffered); stage-2 = 1 ds_read + row8_sum.
// Paired-reciprocal: r = rcp(x*y) -> 1/x = r*y, 1/y = r*x (halves rcps).
__global__ __launch_bounds__(512) void k_solve(
    const double* __restrict__ W4, const float* __restrict__ omega_init,
    float* __restrict__ ckeepN, float* __restrict__ omegaF)
{
  __shared__ float red[2][64];   // [buf][slot*8 + wave], slots 0..5
  const int t = threadIdx.x;
  const int lane = t & 63, wv = t >> 6;    // 8 waves

  float Wsc[8], fsc[8];
#pragma unroll
  for (int e = 0; e < 8; ++e) {
    Wsc[e] = (float)W4[t * 8 + e];
    int bin = 2 * t + (e >> 2);
    fsc[e] = (float)((double)bin / 1024.0 + (double)(e & 3) / 3072.0 - 0.5);
  }
  v2f frA[4], WrA[4], WfA[4], cnA[4];
#pragma unroll
  for (int i = 0; i < 4; ++i) {
    frA[i] = v2(fsc[2 * i], fsc[2 * i + 1]);
    WrA[i] = v2(Wsc[2 * i], Wsc[2 * i + 1]);
    WfA[i] = WrA[i] * frA[i];
    cnA[i] = sp(0.0f);
  }
  float om0 = omega_init[0], om1 = omega_init[1], om2 = omega_init[2];

#pragma unroll 1
  for (int it = 0; it < 49; ++it) {        // n = 0 .. 48
    float* rb = red[it & 1];
    v2f p0 = sp(0.f), p1 = sp(0.f), p2 = sp(0.f),
        p3 = sp(0.f), p4 = sp(0.f), p5 = sp(0.f);

#pragma unroll
    for (int i = 0; i < 4; ++i) {
      const v2f fv = frA[i];
      v2f a0 = fv - sp(om0), a1 = fv - sp(om1), a2 = fv - sp(om2);
      v2f d0 = a0 * a0, d1 = a1 * a1, d2 = a2 * a2;
      v2f s01 = d0 + d1, s12 = d1 + d2;
      v2f dA = pkfma(sp(ALPHA_F), s01, sp(1.0f));   // 1 + a(d0+d1)
      v2f dC = pkfma(sp(ALPHA_F), s12, sp(1.0f));   // 1 + a(d1+d2)
      v2f dB = pkfma(sp(ALPHA_F), d2, dA);          // 1 + a(d0+d1+d2)
      v2f AB = dA * dB, BC = dB * dC, AC = dA * dC;
      v2f ABC = AB * dC;
      float rr = frcp(ABC.x * ABC.y);               // paired reciprocal
      v2f r = v2(rr * ABC.y, rr * ABC.x);
      v2f w0 = BC * r, w1 = AC * r, w2 = AB * r;
      v2f hf = pkfma(sp(-0.5f), cnA[i], sp(1.0f));
      v2f g = hf * hf;
      v2f gw0 = g * (w0 * w0), gw1 = g * (w1 * w1), gw2 = g * (w2 * w2);
      p0 = pkfma(WfA[i], gw0, p0); p1 = pkfma(WfA[i], gw1, p1);
      p2 = pkfma(WfA[i], gw2, p2);
      p3 = pkfma(WrA[i], gw0, p3); p4 = pkfma(WrA[i], gw1, p4);
      p5 = pkfma(WrA[i], gw2, p5);
      v2f S = (w0 + w1) + w2;
      cnA[i] = pkfma(sp(TAU_F), pkfma(S, hf, sp(-1.0f)), cnA[i]);
    }

    float q0 = p0.x + p0.y, q1 = p1.x + p1.y, q2 = p2.x + p2.y;
    float q3 = p3.x + p3.y, q4 = p4.x + p4.y, q5 = p5.x + p5.y;

    q0 = wave64_sum(q0); q1 = wave64_sum(q1); q2 = wave64_sum(q2);
    q3 = wave64_sum(q3); q4 = wave64_sum(q4); q5 = wave64_sum(q5);
    if (lane == 63) {
      rb[0 * 8 + wv] = q0; rb[1 * 8 + wv] = q1; rb[2 * 8 + wv] = q2;
      rb[3 * 8 + wv] = q3; rb[4 * 8 + wv] = q4; rb[5 * 8 + wv] = q5;
    }
    __syncthreads();                 // the ONLY barrier in the iteration
    // stage 2, redundantly per wave: 6 slots x 8 partials fit in one read
    float v1 = rb[lane];             // slot = lane>>3, idx = lane&7 (lane<48)
    v1 = row8_sum(v1);
    float n0 = rdlane(v1, 7),  n1 = rdlane(v1, 15), n2 = rdlane(v1, 23);
    float e0 = rdlane(v1, 31), e1 = rdlane(v1, 39), e2 = rdlane(v1, 47);
    om0 = n0 * frcp(e0);
    om1 = n1 * frcp(e1);
    om2 = n2 * frcp(e2);
  }

  // entry state of n = 49 (node id = bin*4 + j layout)
  ((float4*)ckeepN)[2 * t]     = make_float4(cnA[0].x, cnA[0].y, cnA[1].x, cnA[1].y);
  ((float4*)ckeepN)[2 * t + 1] = make_float4(cnA[2].x, cnA[2].y, cnA[3].x, cnA[3].y);
  if (t == 0) { omegaF[0] = om0; omegaF[1] = om1; omegaF[2] = om2; }
}

// ---------------- inverse passA (FUSED, dual-FFT): both planes per block ----
__global__ __launch_bounds__(256) void k_inv_A2(
    const float2* __restrict__ fhat, const float* __restrict__ ckeepN,
    const float* __restrict__ omegaF, float2* __restrict__ ws0)
{
  __shared__ __align__(16) v2f A1[PADN2], B1[PADN2], A2[PADN2], B2[PADN2];
  const int tid = threadIdx.x;
  const int b = swz(blockIdx.x);          // 1024 blocks; k1 of s-layout
  const float om0 = omegaF[0], om1 = omegaF[1], om2 = omegaF[2];
  const float xb = (float)b * (1.0f / 1024.0f);
  float l0, l1, l2, l3, m0, m1, m2, m3;
  lag4(xb, l0, l1, l2, l3);
  lag4(1.0f - xb, m0, m1, m2, m3);
  const float4* cN = (const float4*)ckeepN;   // 16KB, L2-resident

  v2f X[4];                               // plane-0 values
  v2f Y[4];                               // plane-1 (V2) values
#pragma unroll
  for (int q = 0; q < 4; ++q) {
    int j = tid + 256 * q;       // k2
    float2 f = fhat[(size_t)b * 1024 + j];
    int bin = j ^ 512;
    int binp = 1023 - bin;
    float4 cv = cN[bin];
    float4 cw = cN[binp];
    float c  = l0 * cv.x + l1 * cv.y + l2 * cv.z + l3 * cv.w;
    float cp = m0 * cw.x + m1 * cw.y + m2 * cw.z + m3 * cw.w;
    float hf = 1.0f - 0.5f * c;
    float hp = 1.0f - 0.5f * cp;
    int tt = (bin << 10) | b;
    float freq = (float)tt * (1.0f / 1048576.0f) - 0.5f;
    v2f fpm = v2(freq, -freq);           // .x: +freq terms (d), .y: -freq (e)
    v2f A0 = fpm - sp(om0), A1v = fpm - sp(om1), A2v = fpm - sp(om2);
    v2f D0 = A0 * A0, D1 = A1v * A1v, D2 = A2v * A2v;
    // plane 0: V0 + i*V1
    v2f DA = pkfma(sp(ALPHA_F), D0 + D1, sp(1.0f));
    v2f DB = pkfma(sp(ALPHA_F), D2, DA);
    float r0 = hf * frcp(DA.x), r0n = hp * frcp(DA.y);
    float r1 = hf * frcp(DB.x), r1n = hp * frcp(DB.y);
    float Rr = 0.5f * (r0 + r0n), Ri = 0.5f * (r1 + r1n);
    X[q] = cmul(v2(f.x, f.y), v2(Rr, Ri));
    // plane 1: V2 (real filter)
    v2f DC = pkfma(sp(ALPHA_F), D1 + D2, sp(1.0f));
    float r2 = hf * frcp(DC.x), r2n = hp * frcp(DC.y);
    float Rr2 = 0.5f * (r2 + r2n);
    Y[q] = v2(f.x, f.y) * sp(Rr2);
  }
  fft1024p_dual<1>(X, Y, A1, B1, A2, B2);

  // output twiddle by recurrence: z(q) = b*(tid+256q)*2^-19, step b/2048
  float sa, ca, ss, cs;
  sincospif((float)(b * tid) * (2.0f / 1048576.0f), &sa, &ca);
  sincospif((float)b * (1.0f / 2048.0f), &ss, &cs);
  v2f E = v2(ca, sa);
  const v2f S = v2(cs, ss);
#pragma unroll
  for (int q = 0; q < 4; ++q) {
    int m1i = tid + 256 * q;
    v2f va = B1[lpad2(m1i)];
    v2f vb = B2[lpad2(m1i)];
    v2f oa = cmul(va, E);
    v2f ob = cmul(vb, E);
    ws0[(size_t)m1i * 1024 + b]           = make_float2(oa.x, oa.y);
    ws0[1048576 + (size_t)m1i * 1024 + b] = make_float2(ob.x, ob.y);
    E = cmul(E, S);
  }
}

// ---------------- inverse passB --------------------------------------------
// blocks [0,1024):  plane 0 -> out0 = Re, out1 = Im
// blocks [1024,1536): plane 1 PAIRED: rows b0=2s, b1=2s+1 Hermitian-combined
__global__ __launch_bounds__(256) void k_inv_B2(const float2* __restrict__ ws0,
                                                float* __restrict__ out)
{
  __shared__ __align__(16) v2f A[PADN2], B[PADN2];
  const int tid = threadIdx.x;
  const float sc = 1.0f / 1048576.0f;

  if (blockIdx.x < 1024) {               // ---- plane 0 ----
    const int b = swz(blockIdx.x);       // m1
    v2f X[4];
#pragma unroll
    for (int q = 0; q < 4; ++q)
      X[q] = ((const v2f*)ws0)[(size_t)b * 1024 + tid + 256 * q];
    fft1024p_reg<1>(X[0], X[1], X[2], X[3], A, B);
#pragma unroll
    for (int q = 0; q < 4; ++q) {
      int m2 = tid + 256 * q;
      v2f v = B[lpad2(m2)];
      out[(size_t)m2 * 1024 + b]           = v.x * sc;   // imf0
      out[1048576 + (size_t)m2 * 1024 + b] = v.y * sc;   // imf1
    }
  } else {                               // ---- plane 1, paired rows ----
    const int s = swzA(blockIdx.x - 1024);   // [0,512)
    const int b0 = 2 * s, b1 = 2 * s + 1;
#pragma unroll
    for (int q = 0; q < 4; ++q) {
      int j = tid + 256 * q;
      A[lpad2(j)] = ((const v2f*)ws0)[1048576 + (size_t)b0 * 1024 + j];
      B[lpad2(j)] = ((const v2f*)ws0)[1048576 + (size_t)b1 * 1024 + j];
    }
    __syncthreads();
    v2f Z[4];
#pragma unroll
    for (int q = 0; q < 4; ++q) {
      int j = tid + 256 * q;
      int mj = (1024 - j) & 1023;
      v2f W0j = A[lpad2(j)], W0m = A[lpad2(mj)];
      v2f W1j = B[lpad2(j)], W1m = B[lpad2(mj)];
      float H0r = 0.5f * (W0j.x + W0m.x), H0i = 0.5f * (W0j.y - W0m.y);
      float H1r = 0.5f * (W1j.x + W1m.x), H1i = 0.5f * (W1j.y - W1m.y);
      Z[q] = v2(H0r - H1i, H0i + H1r);
    }
    __syncthreads();   // all reads of A/B done before stage-0 writes B
    fft1024p_reg<1>(Z[0], Z[1], Z[2], Z[3], A, B);
#pragma unroll
    for (int q = 0; q < 4; ++q) {
      int m2 = tid + 256 * q;
      v2f v = B[lpad2(m2)];
      out[2097152 + (size_t)m2 * 1024 + b0] = v.x * sc;  // imf2 row b0
      out[2097152 + (size_t)m2 * 1024 + b1] = v.y * sc;  // imf2 row b1
    }
  }
}

// ---------------- host launch ----------------
extern "C" void kernel_launch(void* const* d_in, const int* in_sizes, int n_in,
                              void* d_out, int out_size, void* d_ws, size_t ws_size,
                              hipStream_t stream)
{
  (void)in_sizes; (void)n_in; (void)out_size; (void)ws_size;
  const float* x       = (const float*)d_in[0];
  const float* om_init = (const float*)d_in[1];
  float* out = (float*)d_out;

  char* w = (char*)d_ws;
  const size_t MB = 1024ull * 1024ull;
  float2* fhat     = (float2*)(w);
  float*  ET       = (float*)(w + 8 * MB);
  double* W4       = (double*)(w + 12 * MB);            // 4096 doubles (32 KB)
  float*  ckeepN   = (float*)(w + 12 * MB + 32 * 1024); // 4096 floats (16 KB)
  float*  omegaF   = (float*)(w + 12 * MB + 48 * 1024);
  float2* scratch  = (float2*)(w + 16 * MB);            // 2 x 8 MB

  k_fwd_passA<<<512, 256, 0, stream>>>(x, scratch);
  k_fwd_passB<<<1024, 256, 0, stream>>>(scratch, fhat, ET);
  k_moments<<<1024, 256, 0, stream>>>(ET, W4);
  k_solve<<<1, 512, 0, stream>>>(W4, om_init, ckeepN, omegaF);
  k_inv_A2<<<1024, 256, 0, stream>>>(fhat, ckeepN, omegaF, scratch);
  k_inv_B2<<<1536, 256, 0, stream>>>(scratch, out);
}